// Round 2
// baseline (1300.721 us; speedup 1.0000x reference)
//
#include <hip/hip_runtime.h>
#include <math.h>

// ---------------- problem constants (shapes are fixed by the reference) ----
#define NM   8192            // mm nodes
#define NDD  6144            // dd nodes
#define NN   14336           // NM + NDD
#define EMM  131072          // mm edges
#define EDD  98304           // dd edges
#define EGAT 229376          // gat edges (no loops)
#define ETOT (EGAT + NN)     // gat edges + self loops = 243712

// ---------------- helpers --------------------------------------------------
static __device__ __forceinline__ unsigned f2ord(float f) {
  unsigned u = __float_as_uint(f);
  return (u & 0x80000000u) ? ~u : (u | 0x80000000u);
}
static __device__ __forceinline__ float ord2f(unsigned u) {
  return (u & 0x80000000u) ? __uint_as_float(u ^ 0x80000000u) : __uint_as_float(~u);
}

// ---------------- GCN prep -------------------------------------------------
__global__ __launch_bounds__(256) void fill_deg(float* deg) {
  int i = blockIdx.x * 256 + threadIdx.x;
  if (i < NN) deg[i] = 1.0f;   // self-loop weight
}

__global__ __launch_bounds__(256) void gather_deg(
    const float* __restrict__ ms, const float* __restrict__ dsm,
    const int* __restrict__ mmE, const int* __restrict__ ddE,
    float* __restrict__ ew, float* __restrict__ deg) {
  int e = blockIdx.x * 256 + threadIdx.x;
  if (e >= EMM + EDD) return;
  float w; int dg;
  if (e < EMM) {
    int s = mmE[e], d = mmE[EMM + e];
    w = ms[(size_t)s * NM + d]; dg = d;
  } else {
    int e2 = e - EMM;
    int s = ddE[e2], d = ddE[EDD + e2];
    w = dsm[(size_t)s * NDD + d]; dg = d + NM;
  }
  ew[e] = w;
  atomicAdd(deg + dg, w);
}

__global__ __launch_bounds__(256) void make_dinv(float* deg) {
  int i = blockIdx.x * 256 + threadIdx.x;
  if (i < NN) deg[i] = 1.0f / sqrtf(deg[i]);   // deg >= 1 always
}

__global__ __launch_bounds__(256) void make_norm(
    const float* __restrict__ ew, const float* __restrict__ dinv,
    const int* __restrict__ mmE, const int* __restrict__ ddE,
    float* __restrict__ nrm) {
  int e = blockIdx.x * 256 + threadIdx.x;
  if (e >= EMM + EDD) return;
  int sg, dg;
  if (e < EMM) { sg = mmE[e]; dg = mmE[EMM + e]; }
  else { int e2 = e - EMM; sg = ddE[e2] + NM; dg = ddE[EDD + e2] + NM; }
  nrm[e] = dinv[sg] * ew[e] * dinv[dg];
}

// ---------------- tiled fp32 matmul  C[n,K] = act(A[n,F]) @ W[F,K] ---------
// BM rows per block; per-thread 4 rows x 8 cols; W/A may switch at splitRow.
template <int K, bool RELUA, bool BIAS>
__global__ __launch_bounds__(256) void mm_kern(
    const float* __restrict__ Aa, const float* __restrict__ Ab, int splitRow,
    int lda,
    const float* __restrict__ Wa, const float* __restrict__ Wb,
    const float* __restrict__ bias,
    float* __restrict__ C, int F) {
  constexpr int BM = (K == 256) ? 32 : 64;
  constexpr int KC = 32;
  constexpr int NCG = K / 8;               // col-groups of 8 cols
  __shared__ float sA[BM][KC + 1];
  __shared__ float sW[KC][K];
  const int row0 = blockIdx.x * BM;
  const float* A = (row0 < splitRow) ? (Aa + (size_t)row0 * lda)
                                     : (Ab + (size_t)(row0 - splitRow) * lda);
  const float* W = (row0 < splitRow) ? Wa : Wb;
  const int tid = threadIdx.x;
  const int colg = tid % NCG, rowg = tid / NCG;
  const int c0 = colg * 8, r0 = rowg * 4;
  float acc[4][8];
#pragma unroll
  for (int i = 0; i < 4; i++)
#pragma unroll
    for (int j = 0; j < 8; j++) acc[i][j] = 0.f;

  for (int k0 = 0; k0 < F; k0 += KC) {
    __syncthreads();
    for (int i = tid; i < BM * KC; i += 256) {
      int r = i / KC, k = i % KC;
      float v = A[(size_t)r * lda + k0 + k];
      if (RELUA) v = fmaxf(v, 0.f);
      sA[r][k] = v;
    }
    for (int i = tid; i < KC * K; i += 256) {
      int k = i / K, c = i % K;
      sW[k][c] = W[(size_t)(k0 + k) * K + c];
    }
    __syncthreads();
#pragma unroll
    for (int kk = 0; kk < KC; kk++) {
      float a0 = sA[r0][kk], a1 = sA[r0 + 1][kk],
            a2 = sA[r0 + 2][kk], a3 = sA[r0 + 3][kk];
      float w[8];
#pragma unroll
      for (int j = 0; j < 8; j++) w[j] = sW[kk][c0 + j];
#pragma unroll
      for (int j = 0; j < 8; j++) {
        acc[0][j] += a0 * w[j];
        acc[1][j] += a1 * w[j];
        acc[2][j] += a2 * w[j];
        acc[3][j] += a3 * w[j];
      }
    }
  }
#pragma unroll
  for (int i = 0; i < 4; i++) {
    float* Crow = C + (size_t)(row0 + r0 + i) * K + c0;
#pragma unroll
    for (int j = 0; j < 8; j++) {
      float v = acc[i][j];
      if (BIAS) v += bias[c0 + j];
      Crow[j] = v;
    }
  }
}

// ---------------- GCN aggregate --------------------------------------------
// out[i,f] = b[f] + h[i,f]*dinv[i]^2   (self loop), strided output
__global__ __launch_bounds__(256) void gcn_init_kern(
    const float* __restrict__ h, const float* __restrict__ dinv,
    const float* __restrict__ ba, const float* __restrict__ bb,
    float* __restrict__ out, int ldo) {
  int idx = blockIdx.x * 256 + threadIdx.x;
  if (idx >= NN * 128) return;
  int i = idx >> 7, f = idx & 127;
  float di = dinv[i];
  const float* b = (i < NM) ? ba : bb;
  out[(size_t)i * ldo + f] = b[f] + h[idx] * di * di;
}

__global__ __launch_bounds__(256) void gcn_scatter_kern(
    const float* __restrict__ h, const float* __restrict__ nrm,
    const int* __restrict__ mmE, const int* __restrict__ ddE,
    float* __restrict__ out, int ldo) {
  int t = blockIdx.x * 256 + threadIdx.x;
  int e = t >> 7, f = t & 127;           // 2 edges per 256-thread block
  if (e >= EMM + EDD) return;
  int sg, dg;
  if (e < EMM) { sg = mmE[e]; dg = mmE[EMM + e]; }
  else { int e2 = e - EMM; sg = ddE[e2] + NM; dg = ddE[EDD + e2] + NM; }
  float v = h[(size_t)sg * 128 + f] * nrm[e];
  atomicAdd(out + (size_t)dg * ldo + f, v);
}

__global__ __launch_bounds__(256) void relu_strided(float* __restrict__ p, int ldo) {
  int idx = blockIdx.x * 256 + threadIdx.x;
  if (idx >= NN * 128) return;
  int i = idx >> 7, f = idx & 127;
  float* q = p + (size_t)i * ldo + f;
  *q = fmaxf(*q, 0.f);
}

// ---------------- GATv2 ----------------------------------------------------
__global__ __launch_bounds__(256) void gat_init_kern(
    unsigned* __restrict__ mxu, float* __restrict__ den,
    float* __restrict__ acc, int accN) {
  int idx = blockIdx.x * 256 + threadIdx.x;
  if (idx < NN * 4) { mxu[idx] = 0u; den[idx] = 0.f; }  // ord(0) < ord(x) ∀x
  if (idx < accN) acc[idx] = 0.f;
}

// one wave per edge (4 per block); 16 lanes per head reduce the dot with att
template <int C>
__global__ __launch_bounds__(256) void gat_logits_kern(
    const float* __restrict__ xl, const float* __restrict__ xr,
    const int* __restrict__ eidx, const float* __restrict__ att,
    float* __restrict__ lg, unsigned* __restrict__ mxu) {
  constexpr int HC = 4 * C;
  constexpr int CPL = C / 16;
  int e = blockIdx.x * 4 + (threadIdx.x >> 6);
  if (e >= ETOT) return;
  int lane = threadIdx.x & 63;
  int src, dst;
  if (e < EGAT) { src = eidx[e]; dst = eidx[EGAT + e]; }
  else { src = dst = e - EGAT; }
  int h = lane >> 4;
  const float* pl = xl + (size_t)src * HC + h * C;
  const float* pr = xr + (size_t)dst * HC + h * C;
  const float* pa = att + h * C;
  float s = 0.f;
#pragma unroll
  for (int q = 0; q < CPL; q++) {
    int c = (lane & 15) * CPL + q;
    float v = pl[c] + pr[c];
    v = (v > 0.f) ? v : 0.2f * v;
    s += v * pa[c];
  }
  s += __shfl_xor(s, 1); s += __shfl_xor(s, 2);
  s += __shfl_xor(s, 4); s += __shfl_xor(s, 8);
  if ((lane & 15) == 0) {
    lg[(size_t)e * 4 + h] = s;
    atomicMax(mxu + (size_t)dst * 4 + h, f2ord(s));
  }
}

__global__ __launch_bounds__(256) void gat_ex_kern(
    const int* __restrict__ eidx, float* __restrict__ lg,
    const unsigned* __restrict__ mxu, float* __restrict__ den) {
  int idx = blockIdx.x * 256 + threadIdx.x;
  if (idx >= ETOT * 4) return;
  int e = idx >> 2, h = idx & 3;
  int dst = (e < EGAT) ? eidx[EGAT + e] : (e - EGAT);
  float m = ord2f(mxu[(size_t)dst * 4 + h]);
  float x = expf(lg[idx] - m);
  lg[idx] = x;
  atomicAdd(den + (size_t)dst * 4 + h, x);
}

template <int C>
__global__ __launch_bounds__(4 * C) void gat_scatter_kern(
    const float* __restrict__ xl, const float* __restrict__ lg,
    const float* __restrict__ den, const int* __restrict__ eidx,
    float* __restrict__ acc) {
  constexpr int HC = 4 * C;
  int e = blockIdx.x;
  int f = threadIdx.x, h = f / C;
  int src, dst;
  if (e < EGAT) { src = eidx[e]; dst = eidx[EGAT + e]; }
  else { src = dst = e - EGAT; }
  float alpha = lg[(size_t)e * 4 + h] / den[(size_t)dst * 4 + h];
  atomicAdd(acc + (size_t)dst * HC + f, xl[(size_t)src * HC + f] * alpha);
}

template <int C, bool ELU>
__global__ __launch_bounds__(256) void gat_fin_kern(
    const float* __restrict__ acc, const float* __restrict__ bias,
    float* __restrict__ out, int ldo, int outoff) {
  int idx = blockIdx.x * 256 + threadIdx.x;
  if (idx >= NN * C) return;
  int i = idx / C, c = idx % C;
  const float* a = acc + (size_t)i * 4 * C;
  float v = (a[c] + a[C + c] + a[2 * C + c] + a[3 * C + c]) * 0.25f + bias[c];
  if (ELU) v = (v > 0.f) ? v : (expf(v) - 1.f);
  out[(size_t)i * ldo + outoff + c] = v;
}

// ---------------- launch ---------------------------------------------------
extern "C" void kernel_launch(void* const* d_in, const int* in_sizes, int n_in,
                              void* d_out, int out_size, void* d_ws, size_t ws_size,
                              hipStream_t stream) {
  const float* mm_f = (const float*)d_in[0];
  const float* d_sf = (const float*)d_in[1];
  const float* msM  = (const float*)d_in[2];
  const float* dsM  = (const float*)d_in[3];
  const int*   mmE  = (const int*)d_in[4];
  const int*   ddE  = (const int*)d_in[5];
  const int*   eidx = (const int*)d_in[6];
  const float* W_m1 = (const float*)d_in[7];  const float* b_m1 = (const float*)d_in[8];
  const float* W_m2 = (const float*)d_in[9];  const float* b_m2 = (const float*)d_in[10];
  const float* W_d1 = (const float*)d_in[11]; const float* b_d1 = (const float*)d_in[12];
  const float* W_d2 = (const float*)d_in[13]; const float* b_d2 = (const float*)d_in[14];
  const float* Wl1  = (const float*)d_in[15]; const float* Wr1  = (const float*)d_in[16];
  const float* att1 = (const float*)d_in[17]; const float* bias1= (const float*)d_in[18];
  const float* Wl2  = (const float*)d_in[19]; const float* Wr2  = (const float*)d_in[20];
  const float* att2 = (const float*)d_in[21]; const float* bias2= (const float*)d_in[22];
  const float* W_jk = (const float*)d_in[23]; const float* b_jk = (const float*)d_in[24];
  float* out = (float*)d_out;

  // workspace layout (floats)
  float* ws = (float*)d_ws;
  float* ew   = ws;                       // 229376
  float* nrm  = ew + (EMM + EDD);         // 229376
  float* dinv = nrm + (EMM + EDD);        // 14336 (deg -> dinv in place)
  float* h    = dinv + NN;                // 14336*128
  float* m1   = h + (size_t)NN * 128;     // 14336*128
  float* xjk  = m1 + (size_t)NN * 128;    // 14336*224  (x0|x1|x2)
  float* xl   = xjk + (size_t)NN * 224;   // 14336*256
  float* xr   = xl + (size_t)NN * 256;    // 14336*256
  float* lg   = xr + (size_t)NN * 256;    // 243712*4
  unsigned* mxu = (unsigned*)(lg + (size_t)ETOT * 4); // 14336*4
  float* den  = (float*)(mxu + (size_t)NN * 4);       // 14336*4
  float* acc  = den + (size_t)NN * 4;     // 14336*256

  const int BIG = 1 << 30;

  // ---- GCN prep: edge weights, degrees, norms (shared by both layers) ----
  fill_deg<<<(NN + 255) / 256, 256, 0, stream>>>(dinv);
  gather_deg<<<(EMM + EDD + 255) / 256, 256, 0, stream>>>(msM, dsM, mmE, ddE, ew, dinv);
  make_dinv<<<(NN + 255) / 256, 256, 0, stream>>>(dinv);
  make_norm<<<(EMM + EDD + 255) / 256, 256, 0, stream>>>(ew, dinv, mmE, ddE, nrm);

  // ---- GCN layer 1 (both graphs fused; per-row-block W select) ----
  mm_kern<128, false, false><<<NN / 64, 256, 0, stream>>>(
      mm_f, d_sf, NM, 128, W_m1, W_d1, nullptr, h, 128);
  gcn_init_kern<<<NN * 128 / 256, 256, 0, stream>>>(h, dinv, b_m1, b_d1, m1, 128);
  gcn_scatter_kern<<<(EMM + EDD) / 2, 256, 0, stream>>>(h, nrm, mmE, ddE, m1, 128);
  // relu(m1) fused into next matmul's A load

  // ---- GCN layer 2 -> x0 (strided into xjk) ----
  // FIX(R1): was splitRow=BIG -> d-rows used W_m2. Now splitRow=NM with
  // Ab pointing at the d-block of m1 so d-rows get W_d2.
  mm_kern<128, true, false><<<NN / 64, 256, 0, stream>>>(
      m1, m1 + (size_t)NM * 128, NM, 128, W_m2, W_d2, nullptr, h, 128);
  gcn_init_kern<<<NN * 128 / 256, 256, 0, stream>>>(h, dinv, b_m2, b_d2, xjk, 224);
  gcn_scatter_kern<<<(EMM + EDD) / 2, 256, 0, stream>>>(h, nrm, mmE, ddE, xjk, 224);
  relu_strided<<<NN * 128 / 256, 256, 0, stream>>>(xjk, 224);   // x0 = relu(...)

  // ---- GATv2 layer 1 (C=64, HC=256) ----
  mm_kern<256, false, false><<<NN / 32, 256, 0, stream>>>(
      xjk, xjk, BIG, 224, Wl1, Wl1, nullptr, xl, 128);
  mm_kern<256, false, false><<<NN / 32, 256, 0, stream>>>(
      xjk, xjk, BIG, 224, Wr1, Wr1, nullptr, xr, 128);
  gat_init_kern<<<NN * 256 / 256, 256, 0, stream>>>(mxu, den, acc, NN * 256);
  gat_logits_kern<64><<<ETOT / 4, 256, 0, stream>>>(xl, xr, eidx, att1, lg, mxu);
  gat_ex_kern<<<ETOT * 4 / 256, 256, 0, stream>>>(eidx, lg, mxu, den);
  gat_scatter_kern<64><<<ETOT, 256, 0, stream>>>(xl, lg, den, eidx, acc);
  gat_fin_kern<64, true><<<NN * 64 / 256, 256, 0, stream>>>(acc, bias1, xjk, 224, 128);

  // ---- GATv2 layer 2 (C=32, HC=128), x1 read strided from xjk ----
  mm_kern<128, false, false><<<NN / 64, 256, 0, stream>>>(
      xjk + 128, xjk + 128, BIG, 224, Wl2, Wl2, nullptr, xl, 64);
  mm_kern<128, false, false><<<NN / 64, 256, 0, stream>>>(
      xjk + 128, xjk + 128, BIG, 224, Wr2, Wr2, nullptr, xr, 64);
  gat_init_kern<<<NN * 128 / 256, 256, 0, stream>>>(mxu, den, acc, NN * 128);
  gat_logits_kern<32><<<ETOT / 4, 256, 0, stream>>>(xl, xr, eidx, att2, lg, mxu);
  gat_ex_kern<<<ETOT * 4 / 256, 256, 0, stream>>>(eidx, lg, mxu, den);
  gat_scatter_kern<32><<<ETOT, 128, 0, stream>>>(xl, lg, den, eidx, acc);
  gat_fin_kern<32, false><<<NN * 32 / 256, 256, 0, stream>>>(acc, bias2, xjk, 224, 192);

  // ---- JK linear: out = xjk @ W_jk + b_jk ----
  mm_kern<128, false, true><<<NN / 64, 256, 0, stream>>>(
      xjk, xjk, BIG, 224, W_jk, W_jk, b_jk, out, 224);
}

// Round 3
// 874.811 us; speedup vs baseline: 1.4869x; 1.4869x over previous
//
#include <hip/hip_runtime.h>
#include <math.h>

// ---------------- problem constants ----------------------------------------
#define NM   8192
#define NDD  6144
#define NN   14336
#define EMM  131072
#define EDD  98304
#define E2   (EMM + EDD)     // 229376 gcn edges (both graphs, fused node space)
#define EGAT 229376          // gat edges (no self loops)

// ---------------- init ------------------------------------------------------
__global__ __launch_bounds__(256) void init_kern(
    float* __restrict__ deg, int* __restrict__ cg, int* __restrict__ ca) {
  int i = blockIdx.x * 256 + threadIdx.x;
  if (i < NN) { deg[i] = 1.0f; cg[i] = 0; ca[i] = 0; }
}

// edge weights + degree + dst histograms (gcn & gat) in one pass
__global__ __launch_bounds__(256) void hist_kern(
    const float* __restrict__ ms, const float* __restrict__ dsm,
    const int* __restrict__ mmE, const int* __restrict__ ddE,
    const int* __restrict__ eidx,
    float* __restrict__ ew, float* __restrict__ deg,
    int* __restrict__ cnt_gcn, int* __restrict__ cnt_gat) {
  int e = blockIdx.x * 256 + threadIdx.x;
  if (e < E2) {
    float w; int dg;
    if (e < EMM) {
      int s = mmE[e], d = mmE[EMM + e];
      w = ms[(size_t)s * NM + d]; dg = d;
    } else {
      int e2 = e - EMM;
      int s = ddE[e2], d = ddE[EDD + e2];
      w = dsm[(size_t)s * NDD + d]; dg = d + NM;
    }
    ew[e] = w;
    atomicAdd(deg + dg, w);
    atomicAdd(cnt_gcn + dg, 1);
  } else {
    int e2 = e - E2;
    if (e2 < EGAT) atomicAdd(cnt_gat + eidx[EGAT + e2], 1);
  }
}

__global__ __launch_bounds__(256) void make_dinv(float* deg) {
  int i = blockIdx.x * 256 + threadIdx.x;
  if (i < NN) deg[i] = 1.0f / sqrtf(deg[i]);   // deg >= 1 (self loop)
}

// 1-block-per-array exclusive scan over NN (=14*1024) counters
__global__ __launch_bounds__(1024) void scan_kern(
    const int* __restrict__ cntA, int* rsA, int* curA,
    const int* __restrict__ cntB, int* rsB, int* curB) {
  const int* cnt = blockIdx.x ? cntB : cntA;
  int* rs  = blockIdx.x ? rsB : rsA;
  int* cur = blockIdx.x ? curB : curA;
  __shared__ int buf[1024];
  __shared__ int carry;
  int t = threadIdx.x;
  if (t == 0) carry = 0;
  __syncthreads();
  for (int base = 0; base < NN; base += 1024) {
    int v = cnt[base + t];
    buf[t] = v;
    __syncthreads();
    for (int off = 1; off < 1024; off <<= 1) {
      int x = (t >= off) ? buf[t - off] : 0;
      __syncthreads();
      buf[t] += x;
      __syncthreads();
    }
    int excl = carry + buf[t] - v;
    rs[base + t] = excl;
    cur[base + t] = excl;
    int total = buf[1023];
    __syncthreads();
    if (t == 0) carry += total;
    __syncthreads();
  }
  if (t == 0) rs[NN] = carry;
}

// fill both CSRs (gcn stores src + norm; gat stores src)
__global__ __launch_bounds__(256) void fill_kern(
    const int* __restrict__ mmE, const int* __restrict__ ddE,
    const int* __restrict__ eidx,
    const float* __restrict__ ew, const float* __restrict__ dinv,
    int* __restrict__ cur_gcn, int* __restrict__ csrc, float* __restrict__ cw,
    int* __restrict__ cur_gat, int* __restrict__ gsrc) {
  int e = blockIdx.x * 256 + threadIdx.x;
  if (e < E2) {
    int sg, dg;
    if (e < EMM) { sg = mmE[e]; dg = mmE[EMM + e]; }
    else { int e2 = e - EMM; sg = ddE[e2] + NM; dg = ddE[EDD + e2] + NM; }
    float nrm = dinv[sg] * ew[e] * dinv[dg];
    int pos = atomicAdd(cur_gcn + dg, 1);
    csrc[pos] = sg; cw[pos] = nrm;
  } else {
    int e2 = e - E2;
    if (e2 < EGAT) {
      int src = eidx[e2], dst = eidx[EGAT + e2];
      int pos = atomicAdd(cur_gat + dst, 1);
      gsrc[pos] = src;
    }
  }
}

// ---------------- tiled fp32 matmul  C[n,K] = A[n,F] @ W[F,K] ---------------
template <int K, bool BIAS>
__global__ __launch_bounds__(256) void mm_kern(
    const float* __restrict__ Aa, const float* __restrict__ Ab, int splitRow,
    int lda,
    const float* __restrict__ Wa, const float* __restrict__ Wb,
    const float* __restrict__ bias,
    float* __restrict__ C, int F) {
  constexpr int BM = (K == 256) ? 32 : 64;
  constexpr int KC = 32;
  constexpr int NCG = K / 8;
  __shared__ float sA[BM][KC + 1];
  __shared__ float sW[KC][K];
  const int row0 = blockIdx.x * BM;
  const float* A = (row0 < splitRow) ? (Aa + (size_t)row0 * lda)
                                     : (Ab + (size_t)(row0 - splitRow) * lda);
  const float* W = (row0 < splitRow) ? Wa : Wb;
  const int tid = threadIdx.x;
  const int colg = tid % NCG, rowg = tid / NCG;
  const int c0 = colg * 8, r0 = rowg * 4;
  float acc[4][8];
#pragma unroll
  for (int i = 0; i < 4; i++)
#pragma unroll
    for (int j = 0; j < 8; j++) acc[i][j] = 0.f;

  for (int k0 = 0; k0 < F; k0 += KC) {
    __syncthreads();
    for (int i = tid; i < BM * KC; i += 256) {
      int r = i / KC, k = i % KC;
      sA[r][k] = A[(size_t)r * lda + k0 + k];
    }
    for (int i = tid; i < KC * K; i += 256) {
      int k = i / K, c = i % K;
      sW[k][c] = W[(size_t)(k0 + k) * K + c];
    }
    __syncthreads();
#pragma unroll
    for (int kk = 0; kk < KC; kk++) {
      float a0 = sA[r0][kk], a1 = sA[r0 + 1][kk],
            a2 = sA[r0 + 2][kk], a3 = sA[r0 + 3][kk];
      float w[8];
#pragma unroll
      for (int j = 0; j < 8; j++) w[j] = sW[kk][c0 + j];
#pragma unroll
      for (int j = 0; j < 8; j++) {
        acc[0][j] += a0 * w[j];
        acc[1][j] += a1 * w[j];
        acc[2][j] += a2 * w[j];
        acc[3][j] += a3 * w[j];
      }
    }
  }
#pragma unroll
  for (int i = 0; i < 4; i++) {
    float* Crow = C + (size_t)(row0 + r0 + i) * K + c0;
#pragma unroll
    for (int j = 0; j < 8; j++) {
      float v = acc[i][j];
      if (BIAS) v += bias[c0 + j];
      Crow[j] = v;
    }
  }
}

// ---------------- GCN aggregate (gather, no atomics) ------------------------
// out[n,f] = [relu]( b[f] + h[n,f]*dinv[n]^2 + sum_e h[src_e,f]*nrm_e )
template <bool RELU>
__global__ __launch_bounds__(256) void gcn_gather_kern(
    const float* __restrict__ h, const float* __restrict__ dinv,
    const float* __restrict__ ba, const float* __restrict__ bb,
    const int* __restrict__ rs, const int* __restrict__ csrc,
    const float* __restrict__ cw,
    float* __restrict__ out, int ldo) {
  int n = blockIdx.x * 2 + (threadIdx.x >> 7);
  int f = threadIdx.x & 127;
  float di = dinv[n];
  const float* b = (n < NM) ? ba : bb;
  float acc = b[f] + h[(size_t)n * 128 + f] * di * di;
  int p = rs[n], p1 = rs[n + 1];
  for (; p + 1 < p1; p += 2) {     // unroll 2 for load overlap
    int s0 = csrc[p], s1 = csrc[p + 1];
    float w0 = cw[p], w1 = cw[p + 1];
    acc += h[(size_t)s0 * 128 + f] * w0;
    acc += h[(size_t)s1 * 128 + f] * w1;
  }
  if (p < p1) acc += h[(size_t)csrc[p] * 128 + f] * cw[p];
  if (RELU) acc = fmaxf(acc, 0.f);
  out[(size_t)n * ldo + f] = acc;
}

// ---------------- fused GATv2 layer (per-dst gather) ------------------------
// One block per dst node: logits -> segment softmax -> weighted sum -> mean
template <int C, bool ELU>
__global__ __launch_bounds__(4 * C) void gat_gather_kern(
    const float* __restrict__ xl, const float* __restrict__ xr,
    const float* __restrict__ att, const float* __restrict__ bias,
    const int* __restrict__ rs, const int* __restrict__ gsrc,
    float* __restrict__ out, int ldo, int off) {
  constexpr int HC = 4 * C;
  constexpr int VPL = C / 16;          // floats per lane (4 or 2)
  constexpr int WAVES = HC / 64;
  constexpr int CAP = 512;             // max in-degree ~45 for this data
  __shared__ float xr_s[HC], att_s[HC];
  __shared__ float lgb[CAP][4];
  __shared__ float part[WAVES][HC];
  __shared__ float den_s[4];
  int n = blockIdx.x;
  int tid = threadIdx.x, w = tid >> 6, lane = tid & 63;
  xr_s[tid] = xr[(size_t)n * HC + tid];
  att_s[tid] = att[tid];
  int p0 = rs[n];
  int deg = rs[n + 1] - p0;
  int tot = deg + 1;                    // + self loop
  if (tot > CAP) tot = CAP;
  __syncthreads();
  int h0 = lane >> 4;                   // head of this lane's feature group
  // ---- pass 1: per-edge logits (wave per edge) ----
  for (int ee = w; ee < tot; ee += WAVES) {
    int src = (ee < deg) ? gsrc[p0 + ee] : n;
    const float* xlr = xl + (size_t)src * HC + lane * VPL;
    float xv[VPL];
    if constexpr (VPL == 4) {
      float4 t4 = *reinterpret_cast<const float4*>(xlr);
      xv[0] = t4.x; xv[1] = t4.y; xv[2] = t4.z; xv[3] = t4.w;
    } else {
      float2 t2 = *reinterpret_cast<const float2*>(xlr);
      xv[0] = t2.x; xv[1] = t2.y;
    }
    float s = 0.f;
#pragma unroll
    for (int v = 0; v < VPL; v++) {
      int f = lane * VPL + v;
      float t = xv[v] + xr_s[f];
      t = (t > 0.f) ? t : 0.2f * t;
      s += t * att_s[f];
    }
    s += __shfl_xor(s, 1); s += __shfl_xor(s, 2);
    s += __shfl_xor(s, 4); s += __shfl_xor(s, 8);
    if ((lane & 15) == 0) lgb[ee][h0] = s;
  }
  __syncthreads();
  // ---- segment softmax (4 threads, one per head; ~tot iters each) ----
  if (tid < 4) {
    float m = -1e30f;
    for (int ee = 0; ee < tot; ee++) m = fmaxf(m, lgb[ee][tid]);
    float d = 0.f;
    for (int ee = 0; ee < tot; ee++) {
      float x = __expf(lgb[ee][tid] - m);
      lgb[ee][tid] = x; d += x;
    }
    den_s[tid] = d;
  }
  __syncthreads();
  // ---- pass 2: weighted accumulation ----
  float a[VPL];
#pragma unroll
  for (int v = 0; v < VPL; v++) a[v] = 0.f;
  for (int ee = w; ee < tot; ee += WAVES) {
    int src = (ee < deg) ? gsrc[p0 + ee] : n;
    const float* xlr = xl + (size_t)src * HC + lane * VPL;
    float exv = lgb[ee][h0];
    if constexpr (VPL == 4) {
      float4 t4 = *reinterpret_cast<const float4*>(xlr);
      a[0] += t4.x * exv; a[1] += t4.y * exv;
      a[2] += t4.z * exv; a[3] += t4.w * exv;
    } else {
      float2 t2 = *reinterpret_cast<const float2*>(xlr);
      a[0] += t2.x * exv; a[1] += t2.y * exv;
    }
  }
#pragma unroll
  for (int v = 0; v < VPL; v++) part[w][lane * VPL + v] = a[v];
  __syncthreads();
  float sum = 0.f;
#pragma unroll
  for (int w2 = 0; w2 < WAVES; w2++) sum += part[w2][tid];
  sum /= den_s[tid / C];
  __syncthreads();
  part[0][tid] = sum;
  __syncthreads();
  // ---- head mean + bias (+ELU), write strided into xjk ----
  if (tid < C) {
    float vv = 0.25f * (part[0][tid] + part[0][C + tid] +
                        part[0][2 * C + tid] + part[0][3 * C + tid]) + bias[tid];
    if (ELU) vv = (vv > 0.f) ? vv : (__expf(vv) - 1.f);
    out[(size_t)n * ldo + off + tid] = vv;
  }
}

// ---------------- launch ----------------------------------------------------
extern "C" void kernel_launch(void* const* d_in, const int* in_sizes, int n_in,
                              void* d_out, int out_size, void* d_ws, size_t ws_size,
                              hipStream_t stream) {
  const float* mm_f = (const float*)d_in[0];
  const float* d_sf = (const float*)d_in[1];
  const float* msM  = (const float*)d_in[2];
  const float* dsM  = (const float*)d_in[3];
  const int*   mmE  = (const int*)d_in[4];
  const int*   ddE  = (const int*)d_in[5];
  const int*   eidx = (const int*)d_in[6];
  const float* W_m1 = (const float*)d_in[7];  const float* b_m1 = (const float*)d_in[8];
  const float* W_m2 = (const float*)d_in[9];  const float* b_m2 = (const float*)d_in[10];
  const float* W_d1 = (const float*)d_in[11]; const float* b_d1 = (const float*)d_in[12];
  const float* W_d2 = (const float*)d_in[13]; const float* b_d2 = (const float*)d_in[14];
  const float* Wl1  = (const float*)d_in[15]; const float* Wr1  = (const float*)d_in[16];
  const float* att1 = (const float*)d_in[17]; const float* bias1= (const float*)d_in[18];
  const float* Wl2  = (const float*)d_in[19]; const float* Wr2  = (const float*)d_in[20];
  const float* att2 = (const float*)d_in[21]; const float* bias2= (const float*)d_in[22];
  const float* W_jk = (const float*)d_in[23]; const float* b_jk = (const float*)d_in[24];
  float* out = (float*)d_out;

  // workspace layout
  float* ew   = (float*)d_ws;                 // E2
  float* dinv = ew + E2;                      // NN
  float* h    = dinv + NN;                    // NN*128
  float* m1   = h + (size_t)NN * 128;         // NN*128
  float* xjk  = m1 + (size_t)NN * 128;        // NN*224 (x0|x1|x2)
  float* xl   = xjk + (size_t)NN * 224;       // NN*256
  float* xr   = xl + (size_t)NN * 256;        // NN*256
  float* cw   = xr + (size_t)NN * 256;        // E2 (csr norm)
  int* ip      = (int*)(cw + E2);
  int* cnt_gcn = ip;                          // NN
  int* rs_gcn  = cnt_gcn + NN;                // NN+1
  int* cur_gcn = rs_gcn + NN + 1;             // NN
  int* cnt_gat = cur_gcn + NN;                // NN
  int* rs_gat  = cnt_gat + NN;                // NN+1
  int* cur_gat = rs_gat + NN + 1;             // NN
  int* csrc    = cur_gat + NN;                // E2
  int* gsrc    = csrc + E2;                   // EGAT

  const int BIG = 1 << 30;

  // ---- CSR build + GCN norms ----
  init_kern<<<(NN + 255) / 256, 256, 0, stream>>>(dinv, cnt_gcn, cnt_gat);
  hist_kern<<<(E2 + EGAT) / 256, 256, 0, stream>>>(
      msM, dsM, mmE, ddE, eidx, ew, dinv, cnt_gcn, cnt_gat);
  make_dinv<<<(NN + 255) / 256, 256, 0, stream>>>(dinv);
  scan_kern<<<2, 1024, 0, stream>>>(cnt_gcn, rs_gcn, cur_gcn,
                                    cnt_gat, rs_gat, cur_gat);
  fill_kern<<<(E2 + EGAT) / 256, 256, 0, stream>>>(
      mmE, ddE, eidx, ew, dinv, cur_gcn, csrc, cw, cur_gat, gsrc);

  // ---- GCN layer 1 (fused graphs; per-row-block W select) ----
  mm_kern<128, false><<<NN / 64, 256, 0, stream>>>(
      mm_f, d_sf, NM, 128, W_m1, W_d1, nullptr, h, 128);
  gcn_gather_kern<true><<<NN / 2, 256, 0, stream>>>(
      h, dinv, b_m1, b_d1, rs_gcn, csrc, cw, m1, 128);   // m1 = relu(gcn1)

  // ---- GCN layer 2 -> x0 = relu(gcn2) (strided into xjk) ----
  mm_kern<128, false><<<NN / 64, 256, 0, stream>>>(
      m1, m1 + (size_t)NM * 128, NM, 128, W_m2, W_d2, nullptr, h, 128);
  gcn_gather_kern<true><<<NN / 2, 256, 0, stream>>>(
      h, dinv, b_m2, b_d2, rs_gcn, csrc, cw, xjk, 224);

  // ---- GATv2 layer 1 (C=64) ----
  mm_kern<256, false><<<NN / 32, 256, 0, stream>>>(
      xjk, xjk, BIG, 224, Wl1, Wl1, nullptr, xl, 128);
  mm_kern<256, false><<<NN / 32, 256, 0, stream>>>(
      xjk, xjk, BIG, 224, Wr1, Wr1, nullptr, xr, 128);
  gat_gather_kern<64, true><<<NN, 256, 0, stream>>>(
      xl, xr, att1, bias1, rs_gat, gsrc, xjk, 224, 128);

  // ---- GATv2 layer 2 (C=32), x1 read strided from xjk ----
  mm_kern<128, false><<<NN / 64, 256, 0, stream>>>(
      xjk + 128, xjk + 128, BIG, 224, Wl2, Wl2, nullptr, xl, 64);
  mm_kern<128, false><<<NN / 64, 256, 0, stream>>>(
      xjk + 128, xjk + 128, BIG, 224, Wr2, Wr2, nullptr, xr, 64);
  gat_gather_kern<32, false><<<NN, 128, 0, stream>>>(
      xl, xr, att2, bias2, rs_gat, gsrc, xjk, 224, 192);

  // ---- JK linear ----
  mm_kern<128, true><<<NN / 64, 256, 0, stream>>>(
      xjk, xjk, BIG, 224, W_jk, W_jk, b_jk, out, 224);
}

// Round 4
// 783.340 us; speedup vs baseline: 1.6605x; 1.1168x over previous
//
#include <hip/hip_runtime.h>
#include <math.h>

// ---------------- problem constants ----------------------------------------
#define NM   8192
#define NDD  6144
#define NN   14336
#define EMM  131072
#define EDD  98304
#define E2   (EMM + EDD)     // 229376 gcn edges (both graphs, fused node space)
#define EGAT 229376          // gat edges (no self loops)

typedef __attribute__((ext_vector_type(8))) short bf16x8;
typedef __attribute__((ext_vector_type(4))) float f32x4;

// ---------------- bf16 split helpers ---------------------------------------
static __device__ __forceinline__ ushort f2bf(float x) {
  unsigned u = __float_as_uint(x);
  unsigned r = (u + 0x7FFFu + ((u >> 16) & 1u)) >> 16;
  return (ushort)r;
}
static __device__ __forceinline__ float bf2f(ushort h) {
  return __uint_as_float(((unsigned)h) << 16);
}
static __device__ __forceinline__ void split_store(float x, ushort* ph, ushort* pl) {
  ushort hh = f2bf(x);
  *ph = hh;
  *pl = f2bf(x - bf2f(hh));
}

// ---------------- init ------------------------------------------------------
__global__ __launch_bounds__(256) void init_kern(
    float* __restrict__ deg, int* __restrict__ cg, int* __restrict__ ca) {
  int i = blockIdx.x * 256 + threadIdx.x;
  if (i < NN) { deg[i] = 1.0f; cg[i] = 0; ca[i] = 0; }
}

// edge weights + degree + dst histograms (gcn & gat) in one pass
__global__ __launch_bounds__(256) void hist_kern(
    const float* __restrict__ ms, const float* __restrict__ dsm,
    const int* __restrict__ mmE, const int* __restrict__ ddE,
    const int* __restrict__ eidx,
    float* __restrict__ ew, float* __restrict__ deg,
    int* __restrict__ cnt_gcn, int* __restrict__ cnt_gat) {
  int e = blockIdx.x * 256 + threadIdx.x;
  if (e < E2) {
    float w; int dg;
    if (e < EMM) {
      int s = mmE[e], d = mmE[EMM + e];
      w = ms[(size_t)s * NM + d]; dg = d;
    } else {
      int e2 = e - EMM;
      int s = ddE[e2], d = ddE[EDD + e2];
      w = dsm[(size_t)s * NDD + d]; dg = d + NM;
    }
    ew[e] = w;
    atomicAdd(deg + dg, w);
    atomicAdd(cnt_gcn + dg, 1);
  } else {
    int e2 = e - E2;
    if (e2 < EGAT) atomicAdd(cnt_gat + eidx[EGAT + e2], 1);
  }
}

__global__ __launch_bounds__(256) void make_dinv(float* deg) {
  int i = blockIdx.x * 256 + threadIdx.x;
  if (i < NN) deg[i] = 1.0f / sqrtf(deg[i]);   // deg >= 1 (self loop)
}

// 1-block-per-array exclusive scan over NN (=14*1024) counters
__global__ __launch_bounds__(1024) void scan_kern(
    const int* __restrict__ cntA, int* rsA, int* curA,
    const int* __restrict__ cntB, int* rsB, int* curB) {
  const int* cnt = blockIdx.x ? cntB : cntA;
  int* rs  = blockIdx.x ? rsB : rsA;
  int* cur = blockIdx.x ? curB : curA;
  __shared__ int buf[1024];
  __shared__ int carry;
  int t = threadIdx.x;
  if (t == 0) carry = 0;
  __syncthreads();
  for (int base = 0; base < NN; base += 1024) {
    int v = cnt[base + t];
    buf[t] = v;
    __syncthreads();
    for (int off = 1; off < 1024; off <<= 1) {
      int x = (t >= off) ? buf[t - off] : 0;
      __syncthreads();
      buf[t] += x;
      __syncthreads();
    }
    int excl = carry + buf[t] - v;
    rs[base + t] = excl;
    cur[base + t] = excl;
    int total = buf[1023];
    __syncthreads();
    if (t == 0) carry += total;
    __syncthreads();
  }
  if (t == 0) rs[NN] = carry;
}

// fill both CSRs (gcn stores src + norm; gat stores src)
__global__ __launch_bounds__(256) void fill_kern(
    const int* __restrict__ mmE, const int* __restrict__ ddE,
    const int* __restrict__ eidx,
    const float* __restrict__ ew, const float* __restrict__ dinv,
    int* __restrict__ cur_gcn, int* __restrict__ csrc, float* __restrict__ cw,
    int* __restrict__ cur_gat, int* __restrict__ gsrc) {
  int e = blockIdx.x * 256 + threadIdx.x;
  if (e < E2) {
    int sg, dg;
    if (e < EMM) { sg = mmE[e]; dg = mmE[EMM + e]; }
    else { int e2 = e - EMM; sg = ddE[e2] + NM; dg = ddE[EDD + e2] + NM; }
    float nrm = dinv[sg] * ew[e] * dinv[dg];
    int pos = atomicAdd(cur_gcn + dg, 1);
    csrc[pos] = sg; cw[pos] = nrm;
  } else {
    int e2 = e - E2;
    if (e2 < EGAT) {
      int src = eidx[e2], dst = eidx[EGAT + e2];
      int pos = atomicAdd(cur_gat + dst, 1);
      gsrc[pos] = src;
    }
  }
}

// ---------------- weight transpose + bf16 split -----------------------------
// 9 weights W[K][N] f32 -> Wt_h[N][K], Wt_l[N][K] bf16, packed into dst.
__global__ __launch_bounds__(256) void wsplit_kern(
    const float* W0, const float* W1, const float* W2, const float* W3,
    const float* W4, const float* W5, const float* W6, const float* W7,
    const float* W8, ushort* __restrict__ dst) {
  int idx = blockIdx.x * 256 + threadIdx.x;   // [0, 176128)
  const int cum[9] = {16384, 32768, 49152, 65536, 98304, 131072, 139264, 147456, 176128};
  const int Ks[9]  = {128, 128, 128, 128, 128, 128, 64, 64, 224};
  const int Ns[9]  = {128, 128, 128, 128, 256, 256, 128, 128, 128};
  const float* Ws[9] = {W0, W1, W2, W3, W4, W5, W6, W7, W8};
  int seg = 0;
  while (idx >= cum[seg]) seg++;
  int base = seg ? cum[seg - 1] : 0;
  int S = cum[seg] - base;
  int o = idx - base;
  int K = Ks[seg], Nn = Ns[seg];
  int n = o / K, k = o - n * K;
  float x = Ws[seg][(size_t)k * Nn + n];
  split_store(x, dst + 2 * (size_t)base + o, dst + 2 * (size_t)base + S + o);
}

// split the two input feature matrices into bf16 hi/lo [NN][128]
__global__ __launch_bounds__(256) void split_in_kern(
    const float* __restrict__ a, const float* __restrict__ b,
    ushort* __restrict__ oh, ushort* __restrict__ ol) {
  int idx = blockIdx.x * 256 + threadIdx.x;   // NN*128
  float x = (idx < NM * 128) ? a[idx] : b[idx - NM * 128];
  split_store(x, oh + idx, ol + idx);
}

// ---------------- MFMA split-bf16 GEMM  C[M][NT] = A[M][KT] @ W[KT][NT] -----
// A given as bf16 hi/lo pair [M][lda] (col offset aoff); W as transposed
// split pair Wt[n][k]. Per wave: one 16x16 tile, W frags in VGPRs, no LDS.
// 3 MFMA per 32-K step: Ah*Wh + Al*Wh + Ah*Wl (Al*Wl ~2^-18, dropped).
template <int KT, int NT, bool BIAS>
__global__ __launch_bounds__(256) void gemm_kern(
    const ushort* __restrict__ Ah, const ushort* __restrict__ Al,
    int lda, int aoff,
    const ushort* __restrict__ WhA, const ushort* __restrict__ WlA,
    const ushort* __restrict__ WhB, const ushort* __restrict__ WlB,
    int splitRow,
    const float* __restrict__ bias,
    float* __restrict__ C, int ldc) {
  constexpr int NS = KT / 32;
  int w = threadIdx.x >> 6, lane = threadIdx.x & 63;
  int m0 = blockIdx.x * 64 + w * 16;
  int n0 = blockIdx.y * 16;
  const ushort* Wh = (m0 < splitRow) ? WhA : WhB;
  const ushort* Wl = (m0 < splitRow) ? WlA : WlB;
  int lm = lane & 15, kg = lane >> 4;
  // B-frag: lane holds W[k][n], n = lane&15, k = kg*8 + j  -> Wt[n][k] b128
  bf16x8 wh[NS], wl[NS];
  const ushort* wp = Wh + (size_t)(n0 + lm) * KT + kg * 8;
  const ushort* wq = Wl + (size_t)(n0 + lm) * KT + kg * 8;
#pragma unroll
  for (int s = 0; s < NS; s++) {
    wh[s] = *reinterpret_cast<const bf16x8*>(wp + s * 32);
    wl[s] = *reinterpret_cast<const bf16x8*>(wq + s * 32);
  }
  // A-frag: lane holds A[m][k], m = lane&15, k = kg*8 + j -> row-major b128
  const ushort* ap = Ah + (size_t)(m0 + lm) * lda + aoff + kg * 8;
  const ushort* aq = Al + (size_t)(m0 + lm) * lda + aoff + kg * 8;
  f32x4 acc = {0.f, 0.f, 0.f, 0.f};
#pragma unroll
  for (int s = 0; s < NS; s++) {
    bf16x8 ah = *reinterpret_cast<const bf16x8*>(ap + s * 32);
    bf16x8 al = *reinterpret_cast<const bf16x8*>(aq + s * 32);
    acc = __builtin_amdgcn_mfma_f32_16x16x32_bf16(ah, wh[s], acc, 0, 0, 0);
    acc = __builtin_amdgcn_mfma_f32_16x16x32_bf16(al, wh[s], acc, 0, 0, 0);
    acc = __builtin_amdgcn_mfma_f32_16x16x32_bf16(ah, wl[s], acc, 0, 0, 0);
  }
  // D: col = lane&15 (= n), row = kg*4 + r (= m within tile)  [m89-verified]
#pragma unroll
  for (int r = 0; r < 4; r++) {
    float v = acc[r];
    if (BIAS) v += bias[n0 + lm];
    C[(size_t)(m0 + kg * 4 + r) * ldc + n0 + lm] = v;
  }
}

// ---------------- GCN aggregate (gather) -> relu -> split-bf16 out ----------
__global__ __launch_bounds__(256) void gcn_gather_kern(
    const float* __restrict__ h, const float* __restrict__ dinv,
    const float* __restrict__ ba, const float* __restrict__ bb,
    const int* __restrict__ rs, const int* __restrict__ csrc,
    const float* __restrict__ cw,
    ushort* __restrict__ outh, ushort* __restrict__ outl, int ldo) {
  int n = blockIdx.x * 2 + (threadIdx.x >> 7);
  int f = threadIdx.x & 127;
  float di = dinv[n];
  const float* b = (n < NM) ? ba : bb;
  float acc = b[f] + h[(size_t)n * 128 + f] * di * di;
  int p = rs[n], p1 = rs[n + 1];
  for (; p + 1 < p1; p += 2) {
    int s0 = csrc[p], s1 = csrc[p + 1];
    float w0 = cw[p], w1 = cw[p + 1];
    acc += h[(size_t)s0 * 128 + f] * w0;
    acc += h[(size_t)s1 * 128 + f] * w1;
  }
  if (p < p1) acc += h[(size_t)csrc[p] * 128 + f] * cw[p];
  acc = fmaxf(acc, 0.f);    // both GCN outputs pass through relu
  size_t o = (size_t)n * ldo + f;
  split_store(acc, outh + o, outl + o);
}

// ---------------- fused GATv2 layer (per-dst gather) ------------------------
template <int C, bool ELU>
__global__ __launch_bounds__(4 * C) void gat_gather_kern(
    const float* __restrict__ xl, const float* __restrict__ xr,
    const float* __restrict__ att, const float* __restrict__ bias,
    const int* __restrict__ rs, const int* __restrict__ gsrc,
    ushort* __restrict__ outh, ushort* __restrict__ outl, int ldo, int off) {
  constexpr int HC = 4 * C;
  constexpr int VPL = C / 16;
  constexpr int WAVES = HC / 64;
  constexpr int CAP = 512;
  __shared__ float xr_s[HC], att_s[HC];
  __shared__ float lgb[CAP][4];
  __shared__ float part[WAVES][HC];
  __shared__ float den_s[4];
  int n = blockIdx.x;
  int tid = threadIdx.x, w = tid >> 6, lane = tid & 63;
  xr_s[tid] = xr[(size_t)n * HC + tid];
  att_s[tid] = att[tid];
  int p0 = rs[n];
  int deg = rs[n + 1] - p0;
  int tot = deg + 1;
  if (tot > CAP) tot = CAP;
  __syncthreads();
  int h0 = lane >> 4;
  for (int ee = w; ee < tot; ee += WAVES) {
    int src = (ee < deg) ? gsrc[p0 + ee] : n;
    const float* xlr = xl + (size_t)src * HC + lane * VPL;
    float xv[VPL];
    if constexpr (VPL == 4) {
      float4 t4 = *reinterpret_cast<const float4*>(xlr);
      xv[0] = t4.x; xv[1] = t4.y; xv[2] = t4.z; xv[3] = t4.w;
    } else {
      float2 t2 = *reinterpret_cast<const float2*>(xlr);
      xv[0] = t2.x; xv[1] = t2.y;
    }
    float s = 0.f;
#pragma unroll
    for (int v = 0; v < VPL; v++) {
      int f = lane * VPL + v;
      float t = xv[v] + xr_s[f];
      t = (t > 0.f) ? t : 0.2f * t;
      s += t * att_s[f];
    }
    s += __shfl_xor(s, 1); s += __shfl_xor(s, 2);
    s += __shfl_xor(s, 4); s += __shfl_xor(s, 8);
    if ((lane & 15) == 0) lgb[ee][h0] = s;
  }
  __syncthreads();
  if (tid < 4) {
    float m = -1e30f;
    for (int ee = 0; ee < tot; ee++) m = fmaxf(m, lgb[ee][tid]);
    float d = 0.f;
    for (int ee = 0; ee < tot; ee++) {
      float x = __expf(lgb[ee][tid] - m);
      lgb[ee][tid] = x; d += x;
    }
    den_s[tid] = d;
  }
  __syncthreads();
  float a[VPL];
#pragma unroll
  for (int v = 0; v < VPL; v++) a[v] = 0.f;
  for (int ee = w; ee < tot; ee += WAVES) {
    int src = (ee < deg) ? gsrc[p0 + ee] : n;
    const float* xlr = xl + (size_t)src * HC + lane * VPL;
    float exv = lgb[ee][h0];
    if constexpr (VPL == 4) {
      float4 t4 = *reinterpret_cast<const float4*>(xlr);
      a[0] += t4.x * exv; a[1] += t4.y * exv;
      a[2] += t4.z * exv; a[3] += t4.w * exv;
    } else {
      float2 t2 = *reinterpret_cast<const float2*>(xlr);
      a[0] += t2.x * exv; a[1] += t2.y * exv;
    }
  }
#pragma unroll
  for (int v = 0; v < VPL; v++) part[w][lane * VPL + v] = a[v];
  __syncthreads();
  float sum = 0.f;
#pragma unroll
  for (int w2 = 0; w2 < WAVES; w2++) sum += part[w2][tid];
  sum /= den_s[tid / C];
  __syncthreads();
  part[0][tid] = sum;
  __syncthreads();
  if (tid < C) {
    float vv = 0.25f * (part[0][tid] + part[0][C + tid] +
                        part[0][2 * C + tid] + part[0][3 * C + tid]) + bias[tid];
    if (ELU) vv = (vv > 0.f) ? vv : (__expf(vv) - 1.f);
    size_t o = (size_t)n * ldo + off + tid;
    split_store(vv, outh + o, outl + o);
  }
}

// ---------------- launch ----------------------------------------------------
extern "C" void kernel_launch(void* const* d_in, const int* in_sizes, int n_in,
                              void* d_out, int out_size, void* d_ws, size_t ws_size,
                              hipStream_t stream) {
  const float* mm_f = (const float*)d_in[0];
  const float* d_sf = (const float*)d_in[1];
  const float* msM  = (const float*)d_in[2];
  const float* dsM  = (const float*)d_in[3];
  const int*   mmE  = (const int*)d_in[4];
  const int*   ddE  = (const int*)d_in[5];
  const int*   eidx = (const int*)d_in[6];
  const float* W_m1 = (const float*)d_in[7];  const float* b_m1 = (const float*)d_in[8];
  const float* W_m2 = (const float*)d_in[9];  const float* b_m2 = (const float*)d_in[10];
  const float* W_d1 = (const float*)d_in[11]; const float* b_d1 = (const float*)d_in[12];
  const float* W_d2 = (const float*)d_in[13]; const float* b_d2 = (const float*)d_in[14];
  const float* Wl1  = (const float*)d_in[15]; const float* Wr1  = (const float*)d_in[16];
  const float* att1 = (const float*)d_in[17]; const float* bias1= (const float*)d_in[18];
  const float* Wl2  = (const float*)d_in[19]; const float* Wr2  = (const float*)d_in[20];
  const float* att2 = (const float*)d_in[21]; const float* bias2= (const float*)d_in[22];
  const float* W_jk = (const float*)d_in[23]; const float* b_jk = (const float*)d_in[24];
  float* out = (float*)d_out;

  // ---- workspace layout ----
  float* ew   = (float*)d_ws;                 // E2
  float* cw   = ew + E2;                      // E2
  float* dinv = cw + E2;                      // NN
  float* h    = dinv + NN;                    // NN*128  (gemm out / gather in)
  float* xl   = h + (size_t)NN * 128;         // NN*256
  float* xr   = xl + (size_t)NN * 256;        // NN*256
  ushort* us   = (ushort*)(xr + (size_t)NN * 256);
  ushort* inh  = us;                          // NN*128
  ushort* inl  = inh + (size_t)NN * 128;      // NN*128
  ushort* m1h  = inl + (size_t)NN * 128;      // NN*128
  ushort* m1l  = m1h + (size_t)NN * 128;      // NN*128
  ushort* xjkh = m1l + (size_t)NN * 128;      // NN*224
  ushort* xjkl = xjkh + (size_t)NN * 224;     // NN*224
  ushort* wts  = xjkl + (size_t)NN * 224;     // 352256
  int* ip      = (int*)(wts + 352256);
  int* cnt_gcn = ip;                          // NN
  int* rs_gcn  = cnt_gcn + NN;                // NN+1
  int* cur_gcn = rs_gcn + NN + 1;             // NN
  int* cnt_gat = cur_gcn + NN;                // NN
  int* rs_gat  = cnt_gat + NN;                // NN+1
  int* cur_gat = rs_gat + NN + 1;             // NN
  int* csrc    = cur_gat + NN;                // E2
  int* gsrc    = csrc + E2;                   // EGAT

  // transposed-split weight offsets (h, l) in wts, ushort units
  ushort* m1Wh = wts + 0;      ushort* m1Wl = wts + 16384;
  ushort* m2Wh = wts + 32768;  ushort* m2Wl = wts + 49152;
  ushort* d1Wh = wts + 65536;  ushort* d1Wl = wts + 81920;
  ushort* d2Wh = wts + 98304;  ushort* d2Wl = wts + 114688;
  ushort* l1Wh = wts + 131072; ushort* l1Wl = wts + 163840;
  ushort* r1Wh = wts + 196608; ushort* r1Wl = wts + 229376;
  ushort* l2Wh = wts + 262144; ushort* l2Wl = wts + 270336;
  ushort* r2Wh = wts + 278528; ushort* r2Wl = wts + 286720;
  ushort* jkWh = wts + 294912; ushort* jkWl = wts + 323584;

  const int BIG = 1 << 30;

  // ---- CSR build + GCN norms + splits ----
  init_kern<<<(NN + 255) / 256, 256, 0, stream>>>(dinv, cnt_gcn, cnt_gat);
  hist_kern<<<(E2 + EGAT) / 256, 256, 0, stream>>>(
      msM, dsM, mmE, ddE, eidx, ew, dinv, cnt_gcn, cnt_gat);
  make_dinv<<<(NN + 255) / 256, 256, 0, stream>>>(dinv);
  scan_kern<<<2, 1024, 0, stream>>>(cnt_gcn, rs_gcn, cur_gcn,
                                    cnt_gat, rs_gat, cur_gat);
  fill_kern<<<(E2 + EGAT) / 256, 256, 0, stream>>>(
      mmE, ddE, eidx, ew, dinv, cur_gcn, csrc, cw, cur_gat, gsrc);
  wsplit_kern<<<688, 256, 0, stream>>>(
      W_m1, W_m2, W_d1, W_d2, Wl1, Wr1, Wl2, Wr2, W_jk, wts);
  split_in_kern<<<NN * 128 / 256, 256, 0, stream>>>(mm_f, d_sf, inh, inl);

  // ---- GCN layer 1 ----
  gemm_kern<128, 128, false><<<dim3(NN / 64, 8), 256, 0, stream>>>(
      inh, inl, 128, 0, m1Wh, m1Wl, d1Wh, d1Wl, NM, nullptr, h, 128);
  gcn_gather_kern<<<NN / 2, 256, 0, stream>>>(
      h, dinv, b_m1, b_d1, rs_gcn, csrc, cw, m1h, m1l, 128);

  // ---- GCN layer 2 -> x0 (split, strided into xjk cols 0..127) ----
  gemm_kern<128, 128, false><<<dim3(NN / 64, 8), 256, 0, stream>>>(
      m1h, m1l, 128, 0, m2Wh, m2Wl, d2Wh, d2Wl, NM, nullptr, h, 128);
  gcn_gather_kern<<<NN / 2, 256, 0, stream>>>(
      h, dinv, b_m2, b_d2, rs_gcn, csrc, cw, xjkh, xjkl, 224);

  // ---- GATv2 layer 1 (C=64): xl/xr = x0 @ Wl1/Wr1 ----
  gemm_kern<128, 256, false><<<dim3(NN / 64, 16), 256, 0, stream>>>(
      xjkh, xjkl, 224, 0, l1Wh, l1Wl, l1Wh, l1Wl, BIG, nullptr, xl, 256);
  gemm_kern<128, 256, false><<<dim3(NN / 64, 16), 256, 0, stream>>>(
      xjkh, xjkl, 224, 0, r1Wh, r1Wl, r1Wh, r1Wl, BIG, nullptr, xr, 256);
  gat_gather_kern<64, true><<<NN, 256, 0, stream>>>(
      xl, xr, att1, bias1, rs_gat, gsrc, xjkh, xjkl, 224, 128);

  // ---- GATv2 layer 2 (C=32): x1 = xjk cols 128..191 ----
  gemm_kern<64, 128, false><<<dim3(NN / 64, 8), 256, 0, stream>>>(
      xjkh, xjkl, 224, 128, l2Wh, l2Wl, l2Wh, l2Wl, BIG, nullptr, xl, 128);
  gemm_kern<64, 128, false><<<dim3(NN / 64, 8), 256, 0, stream>>>(
      xjkh, xjkl, 224, 128, r2Wh, r2Wl, r2Wh, r2Wl, BIG, nullptr, xr, 128);
  gat_gather_kern<32, false><<<NN, 128, 0, stream>>>(
      xl, xr, att2, bias2, rs_gat, gsrc, xjkh, xjkl, 224, 192);

  // ---- JK linear: out = xjk @ W_jk + b_jk ----
  gemm_kern<224, 128, true><<<dim3(NN / 64, 8), 256, 0, stream>>>(
      xjkh, xjkl, 224, 0, jkWh, jkWl, jkWh, jkWl, BIG, b_jk, out, 128);
}

// Round 5
// 695.085 us; speedup vs baseline: 1.8713x; 1.1270x over previous
//
#include <hip/hip_runtime.h>
#include <math.h>

// ---------------- problem constants ----------------------------------------
#define NM   8192
#define NDD  6144
#define NN   14336
#define EMM  131072
#define EDD  98304
#define E2   (EMM + EDD)     // 229376 gcn edges (both graphs, fused node space)
#define EGAT 229376          // gat edges (no self loops)
#define WSEG 176128          // total transposed-weight elements (9 mats)

typedef __attribute__((ext_vector_type(8))) short bf16x8;
typedef __attribute__((ext_vector_type(4))) float f32x4;

// ---------------- bf16 split helpers ---------------------------------------
static __device__ __forceinline__ ushort f2bf(float x) {
  unsigned u = __float_as_uint(x);
  unsigned r = (u + 0x7FFFu + ((u >> 16) & 1u)) >> 16;
  return (ushort)r;
}
static __device__ __forceinline__ float bf2f(ushort h) {
  return __uint_as_float(((unsigned)h) << 16);
}
static __device__ __forceinline__ void split_store(float x, ushort* ph, ushort* pl) {
  ushort hh = f2bf(x);
  *ph = hh;
  *pl = f2bf(x - bf2f(hh));
}

// ---------------- prep: zero counters + weight transpose/split + input split
__global__ __launch_bounds__(256) void prep_kern(
    float* __restrict__ deg, int* __restrict__ cg, int* __restrict__ ca,
    const float* W0, const float* W1, const float* W2, const float* W3,
    const float* W4, const float* W5, const float* W6, const float* W7,
    const float* W8, ushort* __restrict__ wdst,
    const float* __restrict__ fa, const float* __restrict__ fb,
    ushort* __restrict__ oh, ushort* __restrict__ ol) {
  int idx = blockIdx.x * 256 + threadIdx.x;
  if (idx < NN) { deg[idx] = 1.0f; cg[idx] = 0; ca[idx] = 0; }
  int i1 = idx - NN;
  if (i1 >= 0 && i1 < WSEG) {
    const int cum[9] = {16384, 32768, 49152, 65536, 98304, 131072, 139264, 147456, 176128};
    const int Ks[9]  = {128, 128, 128, 128, 128, 128, 64, 64, 224};
    const int Ns[9]  = {128, 128, 128, 128, 256, 256, 128, 128, 128};
    const float* Ws[9] = {W0, W1, W2, W3, W4, W5, W6, W7, W8};
    int seg = 0;
    while (i1 >= cum[seg]) seg++;
    int base = seg ? cum[seg - 1] : 0;
    int S = cum[seg] - base;
    int o = i1 - base;
    int K = Ks[seg], Nn = Ns[seg];
    int n = o / K, k = o - n * K;
    float x = Ws[seg][(size_t)k * Nn + n];
    split_store(x, wdst + 2 * (size_t)base + o, wdst + 2 * (size_t)base + S + o);
  }
  int i2 = idx - (NN + WSEG);
  if (i2 >= 0 && i2 < NN * 128) {
    float x = (i2 < NM * 128) ? fa[i2] : fb[i2 - NM * 128];
    split_store(x, oh + i2, ol + i2);
  }
}

// edge weights + degree + dst histograms (gcn & gat) in one pass
__global__ __launch_bounds__(256) void hist_kern(
    const float* __restrict__ ms, const float* __restrict__ dsm,
    const int* __restrict__ mmE, const int* __restrict__ ddE,
    const int* __restrict__ eidx,
    float* __restrict__ ew, float* __restrict__ deg,
    int* __restrict__ cnt_gcn, int* __restrict__ cnt_gat) {
  int e = blockIdx.x * 256 + threadIdx.x;
  if (e < E2) {
    float w; int dg;
    if (e < EMM) {
      int s = mmE[e], d = mmE[EMM + e];
      w = ms[(size_t)s * NM + d]; dg = d;
    } else {
      int e2 = e - EMM;
      int s = ddE[e2], d = ddE[EDD + e2];
      w = dsm[(size_t)s * NDD + d]; dg = d + NM;
    }
    ew[e] = w;
    atomicAdd(deg + dg, w);
    atomicAdd(cnt_gcn + dg, 1);
  } else {
    int e2 = e - E2;
    if (e2 < EGAT) atomicAdd(cnt_gat + eidx[EGAT + e2], 1);
  }
}

// shfl-based exclusive scan (2 blocks, one per CSR) + dinv fold-in
__global__ __launch_bounds__(1024) void scan_kern(
    const int* __restrict__ cntA, int* rsA, int* curA,
    const int* __restrict__ cntB, int* rsB, int* curB,
    float* __restrict__ deg) {
  const int* cnt = blockIdx.x ? cntB : cntA;
  int* rs  = blockIdx.x ? rsB : rsA;
  int* cur = blockIdx.x ? curB : curA;
  // fold: deg -> dinv (block0: first half, block1: second half)
  for (int i = threadIdx.x; i < NN / 2; i += 1024) {
    int j = blockIdx.x * (NN / 2) + i;
    deg[j] = 1.0f / sqrtf(deg[j]);
  }
  __shared__ int wsum[16];
  __shared__ int carry_s;
  int t = threadIdx.x, w = t >> 6, lane = t & 63;
  if (t == 0) carry_s = 0;
  __syncthreads();
  for (int base = 0; base < NN; base += 1024) {
    int v = cnt[base + t];
    int inc = v;
#pragma unroll
    for (int off = 1; off < 64; off <<= 1) {
      int x = __shfl_up(inc, off);
      if (lane >= off) inc += x;
    }
    if (lane == 63) wsum[w] = inc;
    __syncthreads();
    int carry = carry_s;
    if (w == 0 && lane < 16) {
      int s = wsum[lane];
#pragma unroll
      for (int off = 1; off < 16; off <<= 1) {
        int x = __shfl_up(s, off);
        if (lane >= off) s += x;
      }
      wsum[lane] = s;
    }
    __syncthreads();
    int woff = w ? wsum[w - 1] : 0;
    int excl = carry + woff + inc - v;
    rs[base + t] = excl;
    cur[base + t] = excl;
    if (t == 0) carry_s = carry + wsum[15];
    __syncthreads();
  }
  if (threadIdx.x == 0) rs[NN] = carry_s;
}

// fill both CSRs (gcn stores src + norm; gat stores src)
__global__ __launch_bounds__(256) void fill_kern(
    const int* __restrict__ mmE, const int* __restrict__ ddE,
    const int* __restrict__ eidx,
    const float* __restrict__ ew, const float* __restrict__ dinv,
    int* __restrict__ cur_gcn, int* __restrict__ csrc, float* __restrict__ cw,
    int* __restrict__ cur_gat, int* __restrict__ gsrc) {
  int e = blockIdx.x * 256 + threadIdx.x;
  if (e < E2) {
    int sg, dg;
    if (e < EMM) { sg = mmE[e]; dg = mmE[EMM + e]; }
    else { int e2 = e - EMM; sg = ddE[e2] + NM; dg = ddE[EDD + e2] + NM; }
    float nrm = dinv[sg] * ew[e] * dinv[dg];
    int pos = atomicAdd(cur_gcn + dg, 1);
    csrc[pos] = sg; cw[pos] = nrm;
  } else {
    int e2 = e - E2;
    if (e2 < EGAT) {
      int src = eidx[e2], dst = eidx[EGAT + e2];
      int pos = atomicAdd(cur_gat + dst, 1);
      gsrc[pos] = src;
    }
  }
}

// ---------------- MFMA split-bf16 GEMM  C[M][NT] = A[M][KT] @ W[KT][NT] -----
// A-frags held in VGPRs across the full NT column loop (A read once).
// DUAL: blockIdx.y selects (WA->Ca) or (WB->Cb). Else W selected by splitRow.
template <int KT, int NT, bool BIAS, bool DUAL>
__global__ __launch_bounds__(256) void gemm_kern(
    const ushort* __restrict__ Ah, const ushort* __restrict__ Al,
    int lda, int aoff,
    const ushort* __restrict__ WhA, const ushort* __restrict__ WlA,
    const ushort* __restrict__ WhB, const ushort* __restrict__ WlB,
    int splitRow,
    const float* __restrict__ bias,
    float* __restrict__ Ca, float* __restrict__ Cb, int ldc) {
  constexpr int NS = KT / 32;
  int w = threadIdx.x >> 6, lane = threadIdx.x & 63;
  int m0 = blockIdx.x * 64 + w * 16;
  const ushort* Wh; const ushort* Wl; float* C;
  if (DUAL) {
    Wh = blockIdx.y ? WhB : WhA;
    Wl = blockIdx.y ? WlB : WlA;
    C  = blockIdx.y ? Cb : Ca;
  } else {
    Wh = (m0 < splitRow) ? WhA : WhB;
    Wl = (m0 < splitRow) ? WlA : WlB;
    C  = Ca;
  }
  int lm = lane & 15, kg = lane >> 4;
  // A-frag: lane holds A[m][k], m = lane&15, k = kg*8 + j (row-major b128)
  bf16x8 ah[NS], al[NS];
  const ushort* ap = Ah + (size_t)(m0 + lm) * lda + aoff + kg * 8;
  const ushort* aq = Al + (size_t)(m0 + lm) * lda + aoff + kg * 8;
#pragma unroll
  for (int s = 0; s < NS; s++) {
    ah[s] = *reinterpret_cast<const bf16x8*>(ap + s * 32);
    al[s] = *reinterpret_cast<const bf16x8*>(aq + s * 32);
  }
#pragma unroll
  for (int nb = 0; nb < NT / 16; nb++) {
    int n0 = nb * 16;
    // B-frag: lane holds W[k][n], n = lane&15, k = kg*8 + j -> Wt[n][k] b128
    const ushort* wp = Wh + (size_t)(n0 + lm) * KT + kg * 8;
    const ushort* wq = Wl + (size_t)(n0 + lm) * KT + kg * 8;
    f32x4 acc = {0.f, 0.f, 0.f, 0.f};
#pragma unroll
    for (int s = 0; s < NS; s++) {
      bf16x8 wh = *reinterpret_cast<const bf16x8*>(wp + s * 32);
      bf16x8 wl = *reinterpret_cast<const bf16x8*>(wq + s * 32);
      acc = __builtin_amdgcn_mfma_f32_16x16x32_bf16(ah[s], wh, acc, 0, 0, 0);
      acc = __builtin_amdgcn_mfma_f32_16x16x32_bf16(al[s], wh, acc, 0, 0, 0);
      acc = __builtin_amdgcn_mfma_f32_16x16x32_bf16(ah[s], wl, acc, 0, 0, 0);
    }
    // D: col = lane&15 (= n), row = kg*4 + r  [m89-verified]
#pragma unroll
    for (int r = 0; r < 4; r++) {
      float v = acc[r];
      if (BIAS) v += bias[n0 + lm];
      C[(size_t)(m0 + kg * 4 + r) * ldc + n0 + lm] = v;
    }
  }
}

// ---------------- GCN aggregate (gather) -> relu -> split-bf16 out ----------
__global__ __launch_bounds__(256) void gcn_gather_kern(
    const float* __restrict__ h, const float* __restrict__ dinv,
    const float* __restrict__ ba, const float* __restrict__ bb,
    const int* __restrict__ rs, const int* __restrict__ csrc,
    const float* __restrict__ cw,
    ushort* __restrict__ outh, ushort* __restrict__ outl, int ldo) {
  int n = blockIdx.x * 2 + (threadIdx.x >> 7);
  int f = threadIdx.x & 127;
  float di = dinv[n];
  const float* b = (n < NM) ? ba : bb;
  float acc = b[f] + h[(size_t)n * 128 + f] * di * di;
  int p = rs[n], p1 = rs[n + 1];
  for (; p + 1 < p1; p += 2) {
    int s0 = csrc[p], s1 = csrc[p + 1];
    float w0 = cw[p], w1 = cw[p + 1];
    acc += h[(size_t)s0 * 128 + f] * w0;
    acc += h[(size_t)s1 * 128 + f] * w1;
  }
  if (p < p1) acc += h[(size_t)csrc[p] * 128 + f] * cw[p];
  acc = fmaxf(acc, 0.f);    // both GCN outputs pass through relu
  size_t o = (size_t)n * ldo + f;
  split_store(acc, outh + o, outl + o);
}

// ---------------- fused GATv2 layer: single-pass online softmax -------------
// One block per dst node; WAVES waves each own a subset of edges; per-lane
// running (m, d, a[VPL]) online-softmax state; wave partials combined in LDS.
template <int C, bool ELU>
__global__ __launch_bounds__(4 * C) void gat_gather_kern(
    const float* __restrict__ xl, const float* __restrict__ xr,
    const float* __restrict__ att, const float* __restrict__ bias,
    const int* __restrict__ rs, const int* __restrict__ gsrc,
    ushort* __restrict__ outh, ushort* __restrict__ outl, int ldo, int off) {
  constexpr int HC = 4 * C;
  constexpr int VPL = C / 16;          // floats per lane (4 or 2)
  constexpr int WAVES = HC / 64;
  __shared__ float xr_s[HC], att_s[HC];
  __shared__ float aws[WAVES][HC];
  __shared__ float mws[WAVES][4], dws[WAVES][4];
  int n = blockIdx.x;
  int tid = threadIdx.x, w = tid >> 6, lane = tid & 63;
  xr_s[tid] = xr[(size_t)n * HC + tid];
  att_s[tid] = att[tid];
  int p0 = rs[n];
  int deg = rs[n + 1] - p0;
  int tot = deg + 1;                    // + self loop
  __syncthreads();
  int h0 = lane >> 4;
  float xrv[VPL], atv[VPL];
#pragma unroll
  for (int v = 0; v < VPL; v++) {
    xrv[v] = xr_s[lane * VPL + v];
    atv[v] = att_s[lane * VPL + v];
  }
  float m = -1e30f, d = 0.f, a[VPL];
#pragma unroll
  for (int v = 0; v < VPL; v++) a[v] = 0.f;
  for (int ee = w; ee < tot; ee += WAVES) {
    int src = (ee < deg) ? gsrc[p0 + ee] : n;
    const float* xlr = xl + (size_t)src * HC + lane * VPL;
    float xv[VPL];
    if constexpr (VPL == 4) {
      float4 t4 = *reinterpret_cast<const float4*>(xlr);
      xv[0] = t4.x; xv[1] = t4.y; xv[2] = t4.z; xv[3] = t4.w;
    } else {
      float2 t2 = *reinterpret_cast<const float2*>(xlr);
      xv[0] = t2.x; xv[1] = t2.y;
    }
    float s = 0.f;
#pragma unroll
    for (int v = 0; v < VPL; v++) {
      float t = xv[v] + xrv[v];
      t = (t > 0.f) ? t : 0.2f * t;
      s += t * atv[v];
    }
    s += __shfl_xor(s, 1); s += __shfl_xor(s, 2);
    s += __shfl_xor(s, 4); s += __shfl_xor(s, 8);
    // online softmax update (all 16 lanes of the head group have s)
    float mn = fmaxf(m, s);
    float cs = __expf(m - mn);
    float ps = __expf(s - mn);
    d = d * cs + ps;
#pragma unroll
    for (int v = 0; v < VPL; v++) a[v] = a[v] * cs + ps * xv[v];
    m = mn;
  }
#pragma unroll
  for (int v = 0; v < VPL; v++) aws[w][lane * VPL + v] = a[v];
  if ((lane & 15) == 0) { mws[w][h0] = m; dws[w][h0] = d; }
  __syncthreads();
  // combine wave partials; thread tid owns feature tid
  int hh = tid / C;
  float M = mws[0][hh];
#pragma unroll
  for (int w2 = 1; w2 < WAVES; w2++) M = fmaxf(M, mws[w2][hh]);
  float D = 0.f, A = 0.f;
#pragma unroll
  for (int w2 = 0; w2 < WAVES; w2++) {
    float sc = __expf(mws[w2][hh] - M);
    D += dws[w2][hh] * sc;
    A += aws[w2][tid] * sc;
  }
  float sum = A / D;
  __syncthreads();
  aws[0][tid] = sum;
  __syncthreads();
  if (tid < C) {
    float vv = 0.25f * (aws[0][tid] + aws[0][C + tid] +
                        aws[0][2 * C + tid] + aws[0][3 * C + tid]) + bias[tid];
    if (ELU) vv = (vv > 0.f) ? vv : (__expf(vv) - 1.f);
    size_t o = (size_t)n * ldo + off + tid;
    split_store(vv, outh + o, outl + o);
  }
}

// ---------------- launch ----------------------------------------------------
extern "C" void kernel_launch(void* const* d_in, const int* in_sizes, int n_in,
                              void* d_out, int out_size, void* d_ws, size_t ws_size,
                              hipStream_t stream) {
  const float* mm_f = (const float*)d_in[0];
  const float* d_sf = (const float*)d_in[1];
  const float* msM  = (const float*)d_in[2];
  const float* dsM  = (const float*)d_in[3];
  const int*   mmE  = (const int*)d_in[4];
  const int*   ddE  = (const int*)d_in[5];
  const int*   eidx = (const int*)d_in[6];
  const float* W_m1 = (const float*)d_in[7];  const float* b_m1 = (const float*)d_in[8];
  const float* W_m2 = (const float*)d_in[9];  const float* b_m2 = (const float*)d_in[10];
  const float* W_d1 = (const float*)d_in[11]; const float* b_d1 = (const float*)d_in[12];
  const float* W_d2 = (const float*)d_in[13]; const float* b_d2 = (const float*)d_in[14];
  const float* Wl1  = (const float*)d_in[15]; const float* Wr1  = (const float*)d_in[16];
  const float* att1 = (const float*)d_in[17]; const float* bias1= (const float*)d_in[18];
  const float* Wl2  = (const float*)d_in[19]; const float* Wr2  = (const float*)d_in[20];
  const float* att2 = (const float*)d_in[21]; const float* bias2= (const float*)d_in[22];
  const float* W_jk = (const float*)d_in[23]; const float* b_jk = (const float*)d_in[24];
  float* out = (float*)d_out;

  // ---- workspace layout ----
  float* ew   = (float*)d_ws;                 // E2
  float* cw   = ew + E2;                      // E2
  float* dinv = cw + E2;                      // NN (deg -> dinv in place)
  float* h    = dinv + NN;                    // NN*128  (gemm out / gather in)
  float* xl   = h + (size_t)NN * 128;         // NN*256
  float* xr   = xl + (size_t)NN * 256;        // NN*256
  ushort* us   = (ushort*)(xr + (size_t)NN * 256);
  ushort* inh  = us;                          // NN*128
  ushort* inl  = inh + (size_t)NN * 128;      // NN*128
  ushort* m1h  = inl + (size_t)NN * 128;      // NN*128
  ushort* m1l  = m1h + (size_t)NN * 128;      // NN*128
  ushort* xjkh = m1l + (size_t)NN * 128;      // NN*224
  ushort* xjkl = xjkh + (size_t)NN * 224;     // NN*224
  ushort* wts  = xjkl + (size_t)NN * 224;     // 352256
  int* ip      = (int*)(wts + 352256);
  int* cnt_gcn = ip;                          // NN
  int* rs_gcn  = cnt_gcn + NN;                // NN+1
  int* cur_gcn = rs_gcn + NN + 1;             // NN
  int* cnt_gat = cur_gcn + NN;                // NN
  int* rs_gat  = cnt_gat + NN;                // NN+1
  int* cur_gat = rs_gat + NN + 1;             // NN
  int* csrc    = cur_gat + NN;                // E2
  int* gsrc    = csrc + E2;                   // EGAT

  // transposed-split weight offsets (h, l) in wts, ushort units
  ushort* m1Wh = wts + 0;      ushort* m1Wl = wts + 16384;
  ushort* m2Wh = wts + 32768;  ushort* m2Wl = wts + 49152;
  ushort* d1Wh = wts + 65536;  ushort* d1Wl = wts + 81920;
  ushort* d2Wh = wts + 98304;  ushort* d2Wl = wts + 114688;
  ushort* l1Wh = wts + 131072; ushort* l1Wl = wts + 163840;
  ushort* r1Wh = wts + 196608; ushort* r1Wl = wts + 229376;
  ushort* l2Wh = wts + 262144; ushort* l2Wl = wts + 270336;
  ushort* r2Wh = wts + 278528; ushort* r2Wl = wts + 286720;
  ushort* jkWh = wts + 294912; ushort* jkWl = wts + 323584;

  const int BIG = 1 << 30;

  // ---- prep (init + weight split + input split), CSR build, norms ----
  prep_kern<<<(NN + WSEG + NN * 128) / 256, 256, 0, stream>>>(
      dinv, cnt_gcn, cnt_gat,
      W_m1, W_m2, W_d1, W_d2, Wl1, Wr1, Wl2, Wr2, W_jk, wts,
      mm_f, d_sf, inh, inl);
  hist_kern<<<(E2 + EGAT) / 256, 256, 0, stream>>>(
      msM, dsM, mmE, ddE, eidx, ew, dinv, cnt_gcn, cnt_gat);
  scan_kern<<<2, 1024, 0, stream>>>(cnt_gcn, rs_gcn, cur_gcn,
                                    cnt_gat, rs_gat, cur_gat, dinv);
  fill_kern<<<(E2 + EGAT) / 256, 256, 0, stream>>>(
      mmE, ddE, eidx, ew, dinv, cur_gcn, csrc, cw, cur_gat, gsrc);

  // ---- GCN layer 1 ----
  gemm_kern<128, 128, false, false><<<dim3(NN / 64, 1), 256, 0, stream>>>(
      inh, inl, 128, 0, m1Wh, m1Wl, d1Wh, d1Wl, NM, nullptr, h, nullptr, 128);
  gcn_gather_kern<<<NN / 2, 256, 0, stream>>>(
      h, dinv, b_m1, b_d1, rs_gcn, csrc, cw, m1h, m1l, 128);

  // ---- GCN layer 2 -> x0 (split, strided into xjk cols 0..127) ----
  gemm_kern<128, 128, false, false><<<dim3(NN / 64, 1), 256, 0, stream>>>(
      m1h, m1l, 128, 0, m2Wh, m2Wl, d2Wh, d2Wl, NM, nullptr, h, nullptr, 128);
  gcn_gather_kern<<<NN / 2, 256, 0, stream>>>(
      h, dinv, b_m2, b_d2, rs_gcn, csrc, cw, xjkh, xjkl, 224);

  // ---- GATv2 layer 1 (C=64): xl/xr = x0 @ Wl1/Wr1 (fused dual GEMM) ----
  gemm_kern<128, 256, false, true><<<dim3(NN / 64, 2), 256, 0, stream>>>(
      xjkh, xjkl, 224, 0, l1Wh, l1Wl, r1Wh, r1Wl, 0, nullptr, xl, xr, 256);
  gat_gather_kern<64, true><<<NN, 256, 0, stream>>>(
      xl, xr, att1, bias1, rs_gat, gsrc, xjkh, xjkl, 224, 128);

  // ---- GATv2 layer 2 (C=32): x1 = xjk cols 128..191 (fused dual GEMM) ----
  gemm_kern<64, 128, false, true><<<dim3(NN / 64, 2), 256, 0, stream>>>(
      xjkh, xjkl, 224, 128, l2Wh, l2Wl, r2Wh, r2Wl, 0, nullptr, xl, xr, 128);
  gat_gather_kern<32, false><<<NN, 128, 0, stream>>>(
      xl, xr, att2, bias2, rs_gat, gsrc, xjkh, xjkl, 224, 192);

  // ---- JK linear: out = xjk @ W_jk + b_jk ----
  gemm_kern<224, 128, true, false><<<dim3(NN / 64, 1), 256, 0, stream>>>(
      xjkh, xjkl, 224, 0, jkWh, jkWl, jkWh, jkWl, BIG, b_jk, out, nullptr, 128);
}

// Round 7
// 661.239 us; speedup vs baseline: 1.9671x; 1.0512x over previous
//
#include <hip/hip_runtime.h>
#include <math.h>

// ---------------- problem constants ----------------------------------------
#define NM   8192
#define NDD  6144
#define NN   14336
#define EMM  131072
#define EDD  98304
#define E2   (EMM + EDD)     // 229376 gcn edges (both graphs, fused node space)
#define EGAT 229376          // gat edges (no self loops)
#define WSEG 176128          // total transposed-weight elements (9 mats)

typedef __attribute__((ext_vector_type(8))) short bf16x8;
typedef __attribute__((ext_vector_type(4))) float f32x4;

// ---------------- bf16 helpers ----------------------------------------------
static __device__ __forceinline__ ushort f2bf(float x) {
  unsigned u = __float_as_uint(x);
  unsigned r = (u + 0x7FFFu + ((u >> 16) & 1u)) >> 16;
  return (ushort)r;
}
static __device__ __forceinline__ float bf2f(ushort h) {
  return __uint_as_float(((unsigned)h) << 16);
}
static __device__ __forceinline__ void split_store(float x, ushort* ph, ushort* pl) {
  ushort hh = f2bf(x);
  *ph = hh;
  *pl = f2bf(x - bf2f(hh));
}
static __device__ __forceinline__ void unpack2(unsigned u, float& a, float& b) {
  a = __uint_as_float((u & 0xFFFFu) << 16);
  b = __uint_as_float(u & 0xFFFF0000u);
}

// ---------------- prep: zero counters + weight transpose/split + input split
__global__ __launch_bounds__(256) void prep_kern(
    float* __restrict__ deg, int* __restrict__ cg, int* __restrict__ ca,
    const float* W0, const float* W1, const float* W2, const float* W3,
    const float* W4, const float* W5, const float* W6, const float* W7,
    const float* W8, ushort* __restrict__ wdst,
    const float* __restrict__ fa, const float* __restrict__ fb,
    ushort* __restrict__ oh, ushort* __restrict__ ol) {
  int idx = blockIdx.x * 256 + threadIdx.x;
  if (idx < NN) { deg[idx] = 1.0f; cg[idx] = 0; ca[idx] = 0; }
  int i1 = idx - NN;
  if (i1 >= 0 && i1 < WSEG) {
    const int cum[9] = {16384, 32768, 49152, 65536, 98304, 131072, 139264, 147456, 176128};
    const int Ks[9]  = {128, 128, 128, 128, 128, 128, 64, 64, 224};
    const int Ns[9]  = {128, 128, 128, 128, 256, 256, 128, 128, 128};
    const float* Ws[9] = {W0, W1, W2, W3, W4, W5, W6, W7, W8};
    int seg = 0;
    while (i1 >= cum[seg]) seg++;
    int base = seg ? cum[seg - 1] : 0;
    int S = cum[seg] - base;
    int o = i1 - base;
    int K = Ks[seg], Nn = Ns[seg];
    int n = o / K, k = o - n * K;
    float x = Ws[seg][(size_t)k * Nn + n];
    split_store(x, wdst + 2 * (size_t)base + o, wdst + 2 * (size_t)base + S + o);
  }
  int i2 = idx - (NN + WSEG);
  if (i2 >= 0 && i2 < NN * 128) {
    float x = (i2 < NM * 128) ? fa[i2] : fb[i2 - NM * 128];
    split_store(x, oh + i2, ol + i2);
  }
}

// edge weights + degree + dst histograms (gcn & gat) in one pass
__global__ __launch_bounds__(256) void hist_kern(
    const float* __restrict__ ms, const float* __restrict__ dsm,
    const int* __restrict__ mmE, const int* __restrict__ ddE,
    const int* __restrict__ eidx,
    float* __restrict__ ew, float* __restrict__ deg,
    int* __restrict__ cnt_gcn, int* __restrict__ cnt_gat) {
  int e = blockIdx.x * 256 + threadIdx.x;
  if (e < E2) {
    float w; int dg;
    if (e < EMM) {
      int s = mmE[e], d = mmE[EMM + e];
      w = ms[(size_t)s * NM + d]; dg = d;
    } else {
      int e2 = e - EMM;
      int s = ddE[e2], d = ddE[EDD + e2];
      w = dsm[(size_t)s * NDD + d]; dg = d + NM;
    }
    ew[e] = w;
    atomicAdd(deg + dg, w);
    atomicAdd(cnt_gcn + dg, 1);
  } else {
    int e2 = e - E2;
    if (e2 < EGAT) atomicAdd(cnt_gat + eidx[EGAT + e2], 1);
  }
}

// shfl-based exclusive scan (2 blocks, one per CSR) + dinv fold-in
__global__ __launch_bounds__(1024) void scan_kern(
    const int* __restrict__ cntA, int* rsA, int* curA,
    const int* __restrict__ cntB, int* rsB, int* curB,
    float* __restrict__ deg) {
  const int* cnt = blockIdx.x ? cntB : cntA;
  int* rs  = blockIdx.x ? rsB : rsA;
  int* cur = blockIdx.x ? curB : curA;
  for (int i = threadIdx.x; i < NN / 2; i += 1024) {
    int j = blockIdx.x * (NN / 2) + i;
    deg[j] = 1.0f / sqrtf(deg[j]);
  }
  __shared__ int wsum[16];
  __shared__ int carry_s;
  int t = threadIdx.x, w = t >> 6, lane = t & 63;
  if (t == 0) carry_s = 0;
  __syncthreads();
  for (int base = 0; base < NN; base += 1024) {
    int v = cnt[base + t];
    int inc = v;
#pragma unroll
    for (int off = 1; off < 64; off <<= 1) {
      int x = __shfl_up(inc, off);
      if (lane >= off) inc += x;
    }
    if (lane == 63) wsum[w] = inc;
    __syncthreads();
    int carry = carry_s;
    if (w == 0 && lane < 16) {
      int s = wsum[lane];
#pragma unroll
      for (int off = 1; off < 16; off <<= 1) {
        int x = __shfl_up(s, off);
        if (lane >= off) s += x;
      }
      wsum[lane] = s;
    }
    __syncthreads();
    int woff = w ? wsum[w - 1] : 0;
    int excl = carry + woff + inc - v;
    rs[base + t] = excl;
    cur[base + t] = excl;
    if (t == 0) carry_s = carry + wsum[15];
    __syncthreads();
  }
  if (threadIdx.x == 0) rs[NN] = carry_s;
}

// fill both CSRs (gcn stores src + norm; gat stores src)
__global__ __launch_bounds__(256) void fill_kern(
    const int* __restrict__ mmE, const int* __restrict__ ddE,
    const int* __restrict__ eidx,
    const float* __restrict__ ew, const float* __restrict__ dinv,
    int* __restrict__ cur_gcn, int* __restrict__ csrc, float* __restrict__ cw,
    int* __restrict__ cur_gat, int* __restrict__ gsrc) {
  int e = blockIdx.x * 256 + threadIdx.x;
  if (e < E2) {
    int sg, dg;
    if (e < EMM) { sg = mmE[e]; dg = mmE[EMM + e]; }
    else { int e2 = e - EMM; sg = ddE[e2] + NM; dg = ddE[EDD + e2] + NM; }
    float nrm = dinv[sg] * ew[e] * dinv[dg];
    int pos = atomicAdd(cur_gcn + dg, 1);
    csrc[pos] = sg; cw[pos] = nrm;
  } else {
    int e2 = e - E2;
    if (e2 < EGAT) {
      int src = eidx[e2], dst = eidx[EGAT + e2];
      int pos = atomicAdd(cur_gat + dst, 1);
      gsrc[pos] = src;
    }
  }
}

// ---------------- MFMA split-bf16 GEMM  C[M][NT] = A[M][KT] @ W[KT][NT] -----
// A-frags held in VGPRs across the nb loop (A read once per y-split).
// DUAL: blockIdx.z selects (WA -> Ca as bf16) or (WB -> Cb as f32).
template <int KT, int NT, int NSPLIT, bool BIAS, bool DUAL>
__global__ __launch_bounds__(256) void gemm_kern(
    const ushort* __restrict__ Ah, const ushort* __restrict__ Al,
    int lda, int aoff,
    const ushort* __restrict__ WhA, const ushort* __restrict__ WlA,
    const ushort* __restrict__ WhB, const ushort* __restrict__ WlB,
    int splitRow,
    const float* __restrict__ bias,
    void* __restrict__ Ca, void* __restrict__ Cb, int ldc) {
  constexpr int NS = KT / 32;
  constexpr int NBP = (NT / 16) / NSPLIT;
  int w = threadIdx.x >> 6, lane = threadIdx.x & 63;
  int m0 = blockIdx.x * 64 + w * 16;
  bool isA = DUAL ? (blockIdx.z == 0) : (m0 < splitRow);
  const ushort* Wh = isA ? WhA : WhB;
  const ushort* Wl = isA ? WlA : WlB;
  int lm = lane & 15, kg = lane >> 4;
  // A-frag: lane holds A[m][k], m = lane&15, k = kg*8 + j (row-major b128)
  bf16x8 ah[NS], al[NS];
  const ushort* ap = Ah + (size_t)(m0 + lm) * lda + aoff + kg * 8;
  const ushort* aq = Al + (size_t)(m0 + lm) * lda + aoff + kg * 8;
#pragma unroll
  for (int s = 0; s < NS; s++) {
    ah[s] = *reinterpret_cast<const bf16x8*>(ap + s * 32);
    al[s] = *reinterpret_cast<const bf16x8*>(aq + s * 32);
  }
#pragma unroll
  for (int nb = 0; nb < NBP; nb++) {
    int n0 = (blockIdx.y * NBP + nb) * 16;
    const ushort* wp = Wh + (size_t)(n0 + lm) * KT + kg * 8;
    const ushort* wq = Wl + (size_t)(n0 + lm) * KT + kg * 8;
    f32x4 acc = {0.f, 0.f, 0.f, 0.f};
#pragma unroll
    for (int s = 0; s < NS; s++) {
      bf16x8 wh = *reinterpret_cast<const bf16x8*>(wp + s * 32);
      bf16x8 wl = *reinterpret_cast<const bf16x8*>(wq + s * 32);
      acc = __builtin_amdgcn_mfma_f32_16x16x32_bf16(ah[s], wh, acc, 0, 0, 0);
      acc = __builtin_amdgcn_mfma_f32_16x16x32_bf16(al[s], wh, acc, 0, 0, 0);
      acc = __builtin_amdgcn_mfma_f32_16x16x32_bf16(ah[s], wl, acc, 0, 0, 0);
    }
    // D: col = lane&15 (= n), row = kg*4 + r  [m89-verified]
#pragma unroll
    for (int r = 0; r < 4; r++) {
      float v = acc[r];
      if (BIAS) v += bias[n0 + lm];
      size_t o = (size_t)(m0 + kg * 4 + r) * ldc + n0 + lm;
      if (DUAL && blockIdx.z == 0) ((ushort*)Ca)[o] = f2bf(v);
      else if (DUAL) ((float*)Cb)[o] = v;
      else ((float*)Ca)[o] = v;
    }
  }
}

// ---------------- GCN aggregate (gather) -> relu -> split-bf16 out ----------
__global__ __launch_bounds__(256) void gcn_gather_kern(
    const float* __restrict__ h, const float* __restrict__ dinv,
    const float* __restrict__ ba, const float* __restrict__ bb,
    const int* __restrict__ rs, const int* __restrict__ csrc,
    const float* __restrict__ cw,
    ushort* __restrict__ outh, ushort* __restrict__ outl, int ldo) {
  int n = blockIdx.x * 2 + (threadIdx.x >> 7);
  int f = threadIdx.x & 127;
  float di = dinv[n];
  const float* b = (n < NM) ? ba : bb;
  float acc = b[f] + h[(size_t)n * 128 + f] * di * di;
  int p = rs[n], p1 = rs[n + 1];
  for (; p + 3 < p1; p += 4) {      // unroll 4: keep 4 row-gathers in flight
    int s0 = csrc[p], s1 = csrc[p + 1], s2 = csrc[p + 2], s3 = csrc[p + 3];
    float w0 = cw[p], w1 = cw[p + 1], w2 = cw[p + 2], w3 = cw[p + 3];
    float h0 = h[(size_t)s0 * 128 + f];
    float h1 = h[(size_t)s1 * 128 + f];
    float h2 = h[(size_t)s2 * 128 + f];
    float h3 = h[(size_t)s3 * 128 + f];
    acc += h0 * w0 + h1 * w1 + h2 * w2 + h3 * w3;
  }
  for (; p < p1; p++) acc += h[(size_t)csrc[p] * 128 + f] * cw[p];
  acc = fmaxf(acc, 0.f);
  size_t o = (size_t)n * ldo + f;
  split_store(acc, outh + o, outl + o);
}

// ---------------- fused GATv2 layer: single-pass online softmax -------------
// xl is bf16 (gathered ~17x/row); xr f32 (read once, coalesced).
template <int C, bool ELU>
__global__ __launch_bounds__(4 * C) void gat_gather_kern(
    const ushort* __restrict__ xl, const float* __restrict__ xr,
    const float* __restrict__ att, const float* __restrict__ bias,
    const int* __restrict__ rs, const int* __restrict__ gsrc,
    ushort* __restrict__ outh, ushort* __restrict__ outl, int ldo, int off) {
  constexpr int HC = 4 * C;
  constexpr int VPL = C / 16;          // bf16 elems per lane (4 or 2)
  constexpr int WAVES = HC / 64;
  __shared__ float xr_s[HC], att_s[HC];
  __shared__ float aws[WAVES][HC];
  __shared__ float mws[WAVES][4], dws[WAVES][4];
  int n = blockIdx.x;
  int tid = threadIdx.x, w = tid >> 6, lane = tid & 63;
  xr_s[tid] = xr[(size_t)n * HC + tid];
  att_s[tid] = att[tid];
  int p0 = rs[n];
  int deg = rs[n + 1] - p0;
  int tot = deg + 1;                    // + self loop
  __syncthreads();
  int h0 = lane >> 4;
  float xrv[VPL], atv[VPL];
#pragma unroll
  for (int v = 0; v < VPL; v++) {
    xrv[v] = xr_s[lane * VPL + v];
    atv[v] = att_s[lane * VPL + v];
  }
  float m = -1e30f, d = 0.f, a[VPL];
#pragma unroll
  for (int v = 0; v < VPL; v++) a[v] = 0.f;
  // unroll-2: two edges (this wave's ee and ee+WAVES) pipelined per iter
  for (int ee = w; ee < tot; ee += 2 * WAVES) {
    int e1 = ee + WAVES;
    bool has2 = (e1 < tot);
    int src0 = (ee < deg) ? gsrc[p0 + ee] : n;
    int src1 = has2 ? ((e1 < deg) ? gsrc[p0 + e1] : n) : src0;
    float xv0[VPL], xv1[VPL];
    if constexpr (VPL == 4) {
      uint2 r0 = *reinterpret_cast<const uint2*>(xl + (size_t)src0 * HC + lane * 4);
      uint2 r1 = *reinterpret_cast<const uint2*>(xl + (size_t)src1 * HC + lane * 4);
      unpack2(r0.x, xv0[0], xv0[1]); unpack2(r0.y, xv0[2], xv0[3]);
      unpack2(r1.x, xv1[0], xv1[1]); unpack2(r1.y, xv1[2], xv1[3]);
    } else {
      unsigned r0 = *reinterpret_cast<const unsigned*>(xl + (size_t)src0 * HC + lane * 2);
      unsigned r1 = *reinterpret_cast<const unsigned*>(xl + (size_t)src1 * HC + lane * 2);
      unpack2(r0, xv0[0], xv0[1]);
      unpack2(r1, xv1[0], xv1[1]);
    }
    float s0 = 0.f, s1 = 0.f;
#pragma unroll
    for (int v = 0; v < VPL; v++) {
      float t0 = xv0[v] + xrv[v];
      t0 = (t0 > 0.f) ? t0 : 0.2f * t0;
      s0 += t0 * atv[v];
      float t1 = xv1[v] + xrv[v];
      t1 = (t1 > 0.f) ? t1 : 0.2f * t1;
      s1 += t1 * atv[v];
    }
    s0 += __shfl_xor(s0, 1); s0 += __shfl_xor(s0, 2);
    s0 += __shfl_xor(s0, 4); s0 += __shfl_xor(s0, 8);
    s1 += __shfl_xor(s1, 1); s1 += __shfl_xor(s1, 2);
    s1 += __shfl_xor(s1, 4); s1 += __shfl_xor(s1, 8);
    if (!has2) s1 = -1e30f;             // q1 -> 0, xv1 contribution vanishes
    float mn = fmaxf(m, fmaxf(s0, s1));
    float cs = __expf(m - mn);
    float q0 = __expf(s0 - mn);
    float q1 = __expf(s1 - mn);
    d = d * cs + q0 + q1;
#pragma unroll
    for (int v = 0; v < VPL; v++) a[v] = a[v] * cs + q0 * xv0[v] + q1 * xv1[v];
    m = mn;
  }
#pragma unroll
  for (int v = 0; v < VPL; v++) aws[w][lane * VPL + v] = a[v];
  if ((lane & 15) == 0) { mws[w][h0] = m; dws[w][h0] = d; }
  __syncthreads();
  // combine wave partials; thread tid owns feature tid
  int hh = tid / C;
  float M = mws[0][hh];
#pragma unroll
  for (int w2 = 1; w2 < WAVES; w2++) M = fmaxf(M, mws[w2][hh]);
  float D = 0.f, A = 0.f;
#pragma unroll
  for (int w2 = 0; w2 < WAVES; w2++) {
    float sc = __expf(mws[w2][hh] - M);
    D += dws[w2][hh] * sc;
    A += aws[w2][tid] * sc;
  }
  float sum = A / D;
  __syncthreads();
  aws[0][tid] = sum;
  __syncthreads();
  if (tid < C) {
    float vv = 0.25f * (aws[0][tid] + aws[0][C + tid] +
                        aws[0][2 * C + tid] + aws[0][3 * C + tid]) + bias[tid];
    if (ELU) vv = (vv > 0.f) ? vv : (__expf(vv) - 1.f);
    size_t o = (size_t)n * ldo + off + tid;
    split_store(vv, outh + o, outl + o);
  }
}

// ---------------- launch ----------------------------------------------------
extern "C" void kernel_launch(void* const* d_in, const int* in_sizes, int n_in,
                              void* d_out, int out_size, void* d_ws, size_t ws_size,
                              hipStream_t stream) {
  const float* mm_f = (const float*)d_in[0];
  const float* d_sf = (const float*)d_in[1];
  const float* msM  = (const float*)d_in[2];
  const float* dsM  = (const float*)d_in[3];
  const int*   mmE  = (const int*)d_in[4];
  const int*   ddE  = (const int*)d_in[5];
  const int*   eidx = (const int*)d_in[6];
  const float* W_m1 = (const float*)d_in[7];  const float* b_m1 = (const float*)d_in[8];
  const float* W_m2 = (const float*)d_in[9];  const float* b_m2 = (const float*)d_in[10];
  const float* W_d1 = (const float*)d_in[11]; const float* b_d1 = (const float*)d_in[12];
  const float* W_d2 = (const float*)d_in[13]; const float* b_d2 = (const float*)d_in[14];
  const float* Wl1  = (const float*)d_in[15]; const float* Wr1  = (const float*)d_in[16];
  const float* att1 = (const float*)d_in[17]; const float* bias1= (const float*)d_in[18];
  const float* Wl2  = (const float*)d_in[19]; const float* Wr2  = (const float*)d_in[20];
  const float* att2 = (const float*)d_in[21]; const float* bias2= (const float*)d_in[22];
  const float* W_jk = (const float*)d_in[23]; const float* b_jk = (const float*)d_in[24];
  float* out = (float*)d_out;

  // ---- workspace layout ----
  float* ew   = (float*)d_ws;                 // E2
  float* cw   = ew + E2;                      // E2
  float* dinv = cw + E2;                      // NN (deg -> dinv in place)
  float* h    = dinv + NN;                    // NN*128  (gemm out / gather in)
  float* xr   = h + (size_t)NN * 128;         // NN*256 f32 (layer2 uses NN*128)
  ushort* us   = (ushort*)(xr + (size_t)NN * 256);
  ushort* xlb  = us;                          // NN*256 bf16 (layer2 uses NN*128)
  ushort* inh  = xlb + (size_t)NN * 256;      // NN*128
  ushort* inl  = inh + (size_t)NN * 128;      // NN*128
  ushort* m1h  = inl + (size_t)NN * 128;      // NN*128
  ushort* m1l  = m1h + (size_t)NN * 128;      // NN*128
  ushort* xjkh = m1l + (size_t)NN * 128;      // NN*224
  ushort* xjkl = xjkh + (size_t)NN * 224;     // NN*224
  ushort* wts  = xjkl + (size_t)NN * 224;     // 352256
  int* ip      = (int*)(wts + 352256);
  int* cnt_gcn = ip;                          // NN
  int* rs_gcn  = cnt_gcn + NN;                // NN+1
  int* cur_gcn = rs_gcn + NN + 1;             // NN
  int* cnt_gat = cur_gcn + NN;                // NN
  int* rs_gat  = cnt_gat + NN;                // NN+1
  int* cur_gat = rs_gat + NN + 1;             // NN
  int* csrc    = cur_gat + NN;                // E2
  int* gsrc    = csrc + E2;                   // EGAT

  // transposed-split weight offsets (h, l) in wts, ushort units
  ushort* m1Wh = wts + 0;      ushort* m1Wl = wts + 16384;
  ushort* m2Wh = wts + 32768;  ushort* m2Wl = wts + 49152;
  ushort* d1Wh = wts + 65536;  ushort* d1Wl = wts + 81920;
  ushort* d2Wh = wts + 98304;  ushort* d2Wl = wts + 114688;
  ushort* l1Wh = wts + 131072; ushort* l1Wl = wts + 163840;
  ushort* r1Wh = wts + 196608; ushort* r1Wl = wts + 229376;
  ushort* l2Wh = wts + 262144; ushort* l2Wl = wts + 270336;
  ushort* r2Wh = wts + 278528; ushort* r2Wl = wts + 286720;
  ushort* jkWh = wts + 294912; ushort* jkWl = wts + 323584;

  const int BIG = 1 << 30;

  // ---- prep (init + weight split + input split), CSR build, norms ----
  prep_kern<<<(NN + WSEG + NN * 128) / 256, 256, 0, stream>>>(
      dinv, cnt_gcn, cnt_gat,
      W_m1, W_m2, W_d1, W_d2, Wl1, Wr1, Wl2, Wr2, W_jk, wts,
      mm_f, d_sf, inh, inl);
  hist_kern<<<(E2 + EGAT) / 256, 256, 0, stream>>>(
      msM, dsM, mmE, ddE, eidx, ew, dinv, cnt_gcn, cnt_gat);
  scan_kern<<<2, 1024, 0, stream>>>(cnt_gcn, rs_gcn, cur_gcn,
                                    cnt_gat, rs_gat, cur_gat, dinv);
  fill_kern<<<(E2 + EGAT) / 256, 256, 0, stream>>>(
      mmE, ddE, eidx, ew, dinv, cur_gcn, csrc, cw, cur_gat, gsrc);

  // ---- GCN layer 1 ----
  gemm_kern<128, 128, 2, false, false><<<dim3(NN / 64, 2, 1), 256, 0, stream>>>(
      inh, inl, 128, 0, m1Wh, m1Wl, d1Wh, d1Wl, NM, nullptr, h, nullptr, 128);
  gcn_gather_kern<<<NN / 2, 256, 0, stream>>>(
      h, dinv, b_m1, b_d1, rs_gcn, csrc, cw, m1h, m1l, 128);

  // ---- GCN layer 2 -> x0 (split, strided into xjk cols 0..127) ----
  gemm_kern<128, 128, 2, false, false><<<dim3(NN / 64, 2, 1), 256, 0, stream>>>(
      m1h, m1l, 128, 0, m2Wh, m2Wl, d2Wh, d2Wl, NM, nullptr, h, nullptr, 128);
  gcn_gather_kern<<<NN / 2, 256, 0, stream>>>(
      h, dinv, b_m2, b_d2, rs_gcn, csrc, cw, xjkh, xjkl, 224);

  // ---- GATv2 layer 1 (C=64): xl(bf16)/xr(f32) = x0 @ Wl1/Wr1 (dual) ----
  gemm_kern<128, 256, 2, false, true><<<dim3(NN / 64, 2, 2), 256, 0, stream>>>(
      xjkh, xjkl, 224, 0, l1Wh, l1Wl, r1Wh, r1Wl, 0, nullptr, xlb, xr, 256);
  gat_gather_kern<64, true><<<NN, 256, 0, stream>>>(
      xlb, xr, att1, bias1, rs_gat, gsrc, xjkh, xjkl, 224, 128);

  // ---- GATv2 layer 2 (C=32): x1 = xjk cols 128..191 (dual) ----
  gemm_kern<64, 128, 2, false, true><<<dim3(NN / 64, 2, 2), 256, 0, stream>>>(
      xjkh, xjkl, 224, 128, l2Wh, l2Wl, r2Wh, r2Wl, 0, nullptr, xlb, xr, 128);
  gat_gather_kern<32, false><<<NN, 128, 0, stream>>>(
      xlb, xr, att2, bias2, rs_gat, gsrc, xjkh, xjkl, 224, 192);

  // ---- JK linear: out = xjk @ W_jk + b_jk ----
  gemm_kern<224, 128, 2, true, false><<<dim3(NN / 64, 2, 1), 256, 0, stream>>>(
      xjkh, xjkl, 224, 0, jkWh, jkWl, jkWh, jkWl, BIG, b_jk, out, nullptr, 128);
}

// Round 8
// 647.254 us; speedup vs baseline: 2.0096x; 1.0216x over previous
//
#include <hip/hip_runtime.h>
#include <math.h>

// ---------------- problem constants ----------------------------------------
#define NM   8192
#define NDD  6144
#define NN   14336
#define EMM  131072
#define EDD  98304
#define E2   (EMM + EDD)     // 229376 gcn edges (both graphs, fused node space)
#define EGAT 229376          // gat edges (no self loops)
#define WSEG 176128          // total transposed-weight elements (9 mats)

typedef __attribute__((ext_vector_type(8))) short bf16x8;
typedef __attribute__((ext_vector_type(4))) float f32x4;

// ---------------- bf16 helpers ----------------------------------------------
static __device__ __forceinline__ ushort f2bf(float x) {
  unsigned u = __float_as_uint(x);
  unsigned r = (u + 0x7FFFu + ((u >> 16) & 1u)) >> 16;
  return (ushort)r;
}
static __device__ __forceinline__ float bf2f(ushort h) {
  return __uint_as_float(((unsigned)h) << 16);
}
static __device__ __forceinline__ void split_store(float x, ushort* ph, ushort* pl) {
  ushort hh = f2bf(x);
  *ph = hh;
  *pl = f2bf(x - bf2f(hh));
}
static __device__ __forceinline__ void unpack2(unsigned u, float& a, float& b) {
  a = __uint_as_float((u & 0xFFFFu) << 16);
  b = __uint_as_float(u & 0xFFFF0000u);
}

// ---------------- prep: zero counters + weight transpose/split + input split
__global__ __launch_bounds__(256) void prep_kern(
    float* __restrict__ deg, int* __restrict__ cg, int* __restrict__ ca,
    const float* W0, const float* W1, const float* W2, const float* W3,
    const float* W4, const float* W5, const float* W6, const float* W7,
    const float* W8, ushort* __restrict__ wdst,
    const float* __restrict__ fa, const float* __restrict__ fb,
    ushort* __restrict__ oh, ushort* __restrict__ ol) {
  int idx = blockIdx.x * 256 + threadIdx.x;
  if (idx < NN) { deg[idx] = 1.0f; cg[idx] = 0; ca[idx] = 0; }
  int i1 = idx - NN;
  if (i1 >= 0 && i1 < WSEG) {
    const int cum[9] = {16384, 32768, 49152, 65536, 98304, 131072, 139264, 147456, 176128};
    const int Ks[9]  = {128, 128, 128, 128, 128, 128, 64, 64, 224};
    const int Ns[9]  = {128, 128, 128, 128, 256, 256, 128, 128, 128};
    const float* Ws[9] = {W0, W1, W2, W3, W4, W5, W6, W7, W8};
    int seg = 0;
    while (i1 >= cum[seg]) seg++;
    int base = seg ? cum[seg - 1] : 0;
    int S = cum[seg] - base;
    int o = i1 - base;
    int K = Ks[seg], Nn = Ns[seg];
    int n = o / K, k = o - n * K;
    float x = Ws[seg][(size_t)k * Nn + n];
    split_store(x, wdst + 2 * (size_t)base + o, wdst + 2 * (size_t)base + S + o);
  }
  int i2 = idx - (NN + WSEG);
  if (i2 >= 0 && i2 < NN * 128) {
    float x = (i2 < NM * 128) ? fa[i2] : fb[i2 - NM * 128];
    split_store(x, oh + i2, ol + i2);
  }
}

// edge weights + degree + dst histograms (gcn & gat) in one pass
__global__ __launch_bounds__(256) void hist_kern(
    const float* __restrict__ ms, const float* __restrict__ dsm,
    const int* __restrict__ mmE, const int* __restrict__ ddE,
    const int* __restrict__ eidx,
    float* __restrict__ ew, float* __restrict__ deg,
    int* __restrict__ cnt_gcn, int* __restrict__ cnt_gat) {
  int e = blockIdx.x * 256 + threadIdx.x;
  if (e < E2) {
    float w; int dg;
    if (e < EMM) {
      int s = mmE[e], d = mmE[EMM + e];
      w = ms[(size_t)s * NM + d]; dg = d;
    } else {
      int e2 = e - EMM;
      int s = ddE[e2], d = ddE[EDD + e2];
      w = dsm[(size_t)s * NDD + d]; dg = d + NM;
    }
    ew[e] = w;
    atomicAdd(deg + dg, w);
    atomicAdd(cnt_gcn + dg, 1);
  } else {
    int e2 = e - E2;
    if (e2 < EGAT) atomicAdd(cnt_gat + eidx[EGAT + e2], 1);
  }
}

// shfl-based exclusive scan (2 blocks, one per CSR) + dinv fold-in
__global__ __launch_bounds__(1024) void scan_kern(
    const int* __restrict__ cntA, int* rsA, int* curA,
    const int* __restrict__ cntB, int* rsB, int* curB,
    float* __restrict__ deg) {
  const int* cnt = blockIdx.x ? cntB : cntA;
  int* rs  = blockIdx.x ? rsB : rsA;
  int* cur = blockIdx.x ? curB : curA;
  for (int i = threadIdx.x; i < NN / 2; i += 1024) {
    int j = blockIdx.x * (NN / 2) + i;
    deg[j] = 1.0f / sqrtf(deg[j]);
  }
  __shared__ int wsum[16];
  __shared__ int carry_s;
  int t = threadIdx.x, w = t >> 6, lane = t & 63;
  if (t == 0) carry_s = 0;
  __syncthreads();
  for (int base = 0; base < NN; base += 1024) {
    int v = cnt[base + t];
    int inc = v;
#pragma unroll
    for (int off = 1; off < 64; off <<= 1) {
      int x = __shfl_up(inc, off);
      if (lane >= off) inc += x;
    }
    if (lane == 63) wsum[w] = inc;
    __syncthreads();
    int carry = carry_s;
    if (w == 0 && lane < 16) {
      int s = wsum[lane];
#pragma unroll
      for (int off = 1; off < 16; off <<= 1) {
        int x = __shfl_up(s, off);
        if (lane >= off) s += x;
      }
      wsum[lane] = s;
    }
    __syncthreads();
    int woff = w ? wsum[w - 1] : 0;
    int excl = carry + woff + inc - v;
    rs[base + t] = excl;
    cur[base + t] = excl;
    if (t == 0) carry_s = carry + wsum[15];
    __syncthreads();
  }
  if (threadIdx.x == 0) rs[NN] = carry_s;
}

// fill both CSRs (gcn stores src + norm; gat stores src)
__global__ __launch_bounds__(256) void fill_kern(
    const int* __restrict__ mmE, const int* __restrict__ ddE,
    const int* __restrict__ eidx,
    const float* __restrict__ ew, const float* __restrict__ dinv,
    int* __restrict__ cur_gcn, int* __restrict__ csrc, float* __restrict__ cw,
    int* __restrict__ cur_gat, int* __restrict__ gsrc) {
  int e = blockIdx.x * 256 + threadIdx.x;
  if (e < E2) {
    int sg, dg;
    if (e < EMM) { sg = mmE[e]; dg = mmE[EMM + e]; }
    else { int e2 = e - EMM; sg = ddE[e2] + NM; dg = ddE[EDD + e2] + NM; }
    float nrm = dinv[sg] * ew[e] * dinv[dg];
    int pos = atomicAdd(cur_gcn + dg, 1);
    csrc[pos] = sg; cw[pos] = nrm;
  } else {
    int e2 = e - E2;
    if (e2 < EGAT) {
      int src = eidx[e2], dst = eidx[EGAT + e2];
      int pos = atomicAdd(cur_gat + dst, 1);
      gsrc[pos] = src;
    }
  }
}

// ---------------- MFMA split-bf16 GEMM  C[M][NT] = A[M][KT] @ W[KT][NT] -----
// A-frags held in VGPRs across the nb loop (A read once per y-split).
// DUAL: blockIdx.z selects (WA -> Ca as bf16) or (WB -> Cb as f32).
template <int KT, int NT, int NSPLIT, bool BIAS, bool DUAL>
__global__ __launch_bounds__(256) void gemm_kern(
    const ushort* __restrict__ Ah, const ushort* __restrict__ Al,
    int lda, int aoff,
    const ushort* __restrict__ WhA, const ushort* __restrict__ WlA,
    const ushort* __restrict__ WhB, const ushort* __restrict__ WlB,
    int splitRow,
    const float* __restrict__ bias,
    void* __restrict__ Ca, void* __restrict__ Cb, int ldc) {
  constexpr int NS = KT / 32;
  constexpr int NBP = (NT / 16) / NSPLIT;
  int w = threadIdx.x >> 6, lane = threadIdx.x & 63;
  int m0 = blockIdx.x * 64 + w * 16;
  bool isA = DUAL ? (blockIdx.z == 0) : (m0 < splitRow);
  const ushort* Wh = isA ? WhA : WhB;
  const ushort* Wl = isA ? WlA : WlB;
  int lm = lane & 15, kg = lane >> 4;
  // A-frag: lane holds A[m][k], m = lane&15, k = kg*8 + j (row-major b128)
  bf16x8 ah[NS], al[NS];
  const ushort* ap = Ah + (size_t)(m0 + lm) * lda + aoff + kg * 8;
  const ushort* aq = Al + (size_t)(m0 + lm) * lda + aoff + kg * 8;
#pragma unroll
  for (int s = 0; s < NS; s++) {
    ah[s] = *reinterpret_cast<const bf16x8*>(ap + s * 32);
    al[s] = *reinterpret_cast<const bf16x8*>(aq + s * 32);
  }
#pragma unroll
  for (int nb = 0; nb < NBP; nb++) {
    int n0 = (blockIdx.y * NBP + nb) * 16;
    const ushort* wp = Wh + (size_t)(n0 + lm) * KT + kg * 8;
    const ushort* wq = Wl + (size_t)(n0 + lm) * KT + kg * 8;
    f32x4 acc = {0.f, 0.f, 0.f, 0.f};
#pragma unroll
    for (int s = 0; s < NS; s++) {
      bf16x8 wh = *reinterpret_cast<const bf16x8*>(wp + s * 32);
      bf16x8 wl = *reinterpret_cast<const bf16x8*>(wq + s * 32);
      acc = __builtin_amdgcn_mfma_f32_16x16x32_bf16(ah[s], wh, acc, 0, 0, 0);
      acc = __builtin_amdgcn_mfma_f32_16x16x32_bf16(al[s], wh, acc, 0, 0, 0);
      acc = __builtin_amdgcn_mfma_f32_16x16x32_bf16(ah[s], wl, acc, 0, 0, 0);
    }
    // D: col = lane&15 (= n), row = kg*4 + r  [m89-verified]
#pragma unroll
    for (int r = 0; r < 4; r++) {
      float v = acc[r];
      if (BIAS) v += bias[n0 + lm];
      size_t o = (size_t)(m0 + kg * 4 + r) * ldc + n0 + lm;
      if (DUAL && blockIdx.z == 0) ((ushort*)Ca)[o] = f2bf(v);
      else if (DUAL) ((float*)Cb)[o] = v;
      else ((float*)Ca)[o] = v;
    }
  }
}

// ---------------- GCN aggregate (gather) -> relu -> split-bf16 out ----------
// 4 nodes/block, 64 threads/node, float2 per thread (half the load instrs).
__global__ __launch_bounds__(256) void gcn_gather_kern(
    const float* __restrict__ h, const float* __restrict__ dinv,
    const float* __restrict__ ba, const float* __restrict__ bb,
    const int* __restrict__ rs, const int* __restrict__ csrc,
    const float* __restrict__ cw,
    ushort* __restrict__ outh, ushort* __restrict__ outl, int ldo) {
  int n = blockIdx.x * 4 + (threadIdx.x >> 6);
  int f2 = (threadIdx.x & 63) * 2;
  float di = dinv[n];
  const float* b = (n < NM) ? ba : bb;
  float2 hv = *reinterpret_cast<const float2*>(h + (size_t)n * 128 + f2);
  float acc0 = b[f2] + hv.x * di * di;
  float acc1 = b[f2 + 1] + hv.y * di * di;
  int p = rs[n], p1 = rs[n + 1];
  for (; p + 3 < p1; p += 4) {      // 4 rows in flight
    int s0 = csrc[p], s1 = csrc[p + 1], s2 = csrc[p + 2], s3 = csrc[p + 3];
    float w0 = cw[p], w1 = cw[p + 1], w2 = cw[p + 2], w3 = cw[p + 3];
    float2 h0 = *reinterpret_cast<const float2*>(h + (size_t)s0 * 128 + f2);
    float2 h1 = *reinterpret_cast<const float2*>(h + (size_t)s1 * 128 + f2);
    float2 h2 = *reinterpret_cast<const float2*>(h + (size_t)s2 * 128 + f2);
    float2 h3 = *reinterpret_cast<const float2*>(h + (size_t)s3 * 128 + f2);
    acc0 += h0.x * w0 + h1.x * w1 + h2.x * w2 + h3.x * w3;
    acc1 += h0.y * w0 + h1.y * w1 + h2.y * w2 + h3.y * w3;
  }
  for (; p < p1; p++) {
    float2 hx = *reinterpret_cast<const float2*>(h + (size_t)csrc[p] * 128 + f2);
    float wx = cw[p];
    acc0 += hx.x * wx;
    acc1 += hx.y * wx;
  }
  acc0 = fmaxf(acc0, 0.f);
  acc1 = fmaxf(acc1, 0.f);
  size_t o = (size_t)n * ldo + f2;
  split_store(acc0, outh + o, outl + o);
  split_store(acc1, outh + o + 1, outl + o + 1);
}

// ---------------- fused GATv2 layer: single-pass online softmax -------------
// uint4 loads: 8 bf16/lane -> a wave covers SUBW rows per issue; NST parallel
// online-softmax streams per block, combined in LDS at the end.
template <int C, bool ELU>
__global__ __launch_bounds__(4 * C) void gat_gather_kern(
    const ushort* __restrict__ xl, const float* __restrict__ xr,
    const float* __restrict__ att, const float* __restrict__ bias,
    const int* __restrict__ rs, const int* __restrict__ gsrc,
    ushort* __restrict__ outh, ushort* __restrict__ outl, int ldo, int off) {
  constexpr int HC = 4 * C;
  constexpr int LPR = HC / 8;          // lanes per row (32 or 16)
  constexpr int SUBW = 64 / LPR;       // rows per wave issue (2 or 4)
  constexpr int WAVES = HC / 64;       // 4 or 2
  constexpr int NST = WAVES * SUBW;    // 8 edge streams per block
  constexpr int LPH = C / 8;           // lanes per head (8 or 4)
  __shared__ float xr_s[HC], att_s[HC];
  __shared__ float aws[NST][HC];
  __shared__ float mws[NST][4], dws[NST][4];
  int n = blockIdx.x;
  int tid = threadIdx.x, w = tid >> 6, lane = tid & 63;
  xr_s[tid] = xr[(size_t)n * HC + tid];
  att_s[tid] = att[tid];
  int p0 = rs[n];
  int deg = rs[n + 1] - p0;
  int tot = deg + 1;                    // + self loop
  __syncthreads();
  int sg = lane / LPR;                  // sub-wave (stream within wave)
  int lp = lane % LPR;                  // lane within row
  int fbase = lp * 8;
  int hh = fbase / C;                   // head of this lane's 8 features
  int st = w * SUBW + sg;               // stream id in [0, NST)
  float xrv[8], atv[8];
#pragma unroll
  for (int v = 0; v < 8; v++) {
    xrv[v] = xr_s[fbase + v];
    atv[v] = att_s[fbase + v];
  }
  float m = -1e30f, d = 0.f, a[8];
#pragma unroll
  for (int v = 0; v < 8; v++) a[v] = 0.f;
  // unroll-2: streams st and st (next tranche) pipelined per iteration
  for (int ee = st; ee < tot; ee += 2 * NST) {
    int e1 = ee + NST;
    bool has2 = (e1 < tot);
    int src0 = (ee < deg) ? gsrc[p0 + ee] : n;
    int src1 = has2 ? ((e1 < deg) ? gsrc[p0 + e1] : n) : src0;
    uint4 r0 = *reinterpret_cast<const uint4*>(xl + (size_t)src0 * HC + fbase);
    uint4 r1 = *reinterpret_cast<const uint4*>(xl + (size_t)src1 * HC + fbase);
    float xv0[8], xv1[8];
    unpack2(r0.x, xv0[0], xv0[1]); unpack2(r0.y, xv0[2], xv0[3]);
    unpack2(r0.z, xv0[4], xv0[5]); unpack2(r0.w, xv0[6], xv0[7]);
    unpack2(r1.x, xv1[0], xv1[1]); unpack2(r1.y, xv1[2], xv1[3]);
    unpack2(r1.z, xv1[4], xv1[5]); unpack2(r1.w, xv1[6], xv1[7]);
    float s0 = 0.f, s1 = 0.f;
#pragma unroll
    for (int v = 0; v < 8; v++) {
      float t0 = xv0[v] + xrv[v];
      t0 = (t0 > 0.f) ? t0 : 0.2f * t0;
      s0 += t0 * atv[v];
      float t1 = xv1[v] + xrv[v];
      t1 = (t1 > 0.f) ? t1 : 0.2f * t1;
      s1 += t1 * atv[v];
    }
#pragma unroll
    for (int offs = 1; offs < LPH; offs <<= 1) {
      s0 += __shfl_xor(s0, offs);
      s1 += __shfl_xor(s1, offs);
    }
    if (!has2) s1 = -1e30f;             // q1 -> 0, xv1 contribution vanishes
    float mn = fmaxf(m, fmaxf(s0, s1));
    float cs = __expf(m - mn);
    float q0 = __expf(s0 - mn);
    float q1 = __expf(s1 - mn);
    d = d * cs + q0 + q1;
#pragma unroll
    for (int v = 0; v < 8; v++) a[v] = a[v] * cs + q0 * xv0[v] + q1 * xv1[v];
    m = mn;
  }
#pragma unroll
  for (int v = 0; v < 8; v++) aws[st][fbase + v] = a[v];
  if ((lp % LPH) == 0) { mws[st][hh] = m; dws[st][hh] = d; }
  __syncthreads();
  // combine stream partials; thread tid owns feature tid
  int hh2 = tid / C;
  float M = mws[0][hh2];
#pragma unroll
  for (int s2 = 1; s2 < NST; s2++) M = fmaxf(M, mws[s2][hh2]);
  float D = 0.f, A = 0.f;
#pragma unroll
  for (int s2 = 0; s2 < NST; s2++) {
    float sc = __expf(mws[s2][hh2] - M);
    D += dws[s2][hh2] * sc;
    A += aws[s2][tid] * sc;
  }
  float sum = A / D;
  __syncthreads();
  aws[0][tid] = sum;
  __syncthreads();
  if (tid < C) {
    float vv = 0.25f * (aws[0][tid] + aws[0][C + tid] +
                        aws[0][2 * C + tid] + aws[0][3 * C + tid]) + bias[tid];
    if (ELU) vv = (vv > 0.f) ? vv : (__expf(vv) - 1.f);
    size_t o = (size_t)n * ldo + off + tid;
    split_store(vv, outh + o, outl + o);
  }
}

// ---------------- launch ----------------------------------------------------
extern "C" void kernel_launch(void* const* d_in, const int* in_sizes, int n_in,
                              void* d_out, int out_size, void* d_ws, size_t ws_size,
                              hipStream_t stream) {
  const float* mm_f = (const float*)d_in[0];
  const float* d_sf = (const float*)d_in[1];
  const float* msM  = (const float*)d_in[2];
  const float* dsM  = (const float*)d_in[3];
  const int*   mmE  = (const int*)d_in[4];
  const int*   ddE  = (const int*)d_in[5];
  const int*   eidx = (const int*)d_in[6];
  const float* W_m1 = (const float*)d_in[7];  const float* b_m1 = (const float*)d_in[8];
  const float* W_m2 = (const float*)d_in[9];  const float* b_m2 = (const float*)d_in[10];
  const float* W_d1 = (const float*)d_in[11]; const float* b_d1 = (const float*)d_in[12];
  const float* W_d2 = (const float*)d_in[13]; const float* b_d2 = (const float*)d_in[14];
  const float* Wl1  = (const float*)d_in[15]; const float* Wr1  = (const float*)d_in[16];
  const float* att1 = (const float*)d_in[17]; const float* bias1= (const float*)d_in[18];
  const float* Wl2  = (const float*)d_in[19]; const float* Wr2  = (const float*)d_in[20];
  const float* att2 = (const float*)d_in[21]; const float* bias2= (const float*)d_in[22];
  const float* W_jk = (const float*)d_in[23]; const float* b_jk = (const float*)d_in[24];
  float* out = (float*)d_out;

  // ---- workspace layout ----
  float* ew   = (float*)d_ws;                 // E2
  float* cw   = ew + E2;                      // E2
  float* dinv = cw + E2;                      // NN (deg -> dinv in place)
  float* h    = dinv + NN;                    // NN*128  (gemm out / gather in)
  float* xr   = h + (size_t)NN * 128;         // NN*256 f32 (layer2 uses NN*128)
  ushort* us   = (ushort*)(xr + (size_t)NN * 256);
  ushort* xlb  = us;                          // NN*256 bf16 (layer2 uses NN*128)
  ushort* inh  = xlb + (size_t)NN * 256;      // NN*128
  ushort* inl  = inh + (size_t)NN * 128;      // NN*128
  ushort* m1h  = inl + (size_t)NN * 128;      // NN*128
  ushort* m1l  = m1h + (size_t)NN * 128;      // NN*128
  ushort* xjkh = m1l + (size_t)NN * 128;      // NN*224
  ushort* xjkl = xjkh + (size_t)NN * 224;     // NN*224
  ushort* wts  = xjkl + (size_t)NN * 224;     // 352256
  int* ip      = (int*)(wts + 352256);
  int* cnt_gcn = ip;                          // NN
  int* rs_gcn  = cnt_gcn + NN;                // NN+1
  int* cur_gcn = rs_gcn + NN + 1;             // NN
  int* cnt_gat = cur_gcn + NN;                // NN
  int* rs_gat  = cnt_gat + NN;                // NN+1
  int* cur_gat = rs_gat + NN + 1;             // NN
  int* csrc    = cur_gat + NN;                // E2
  int* gsrc    = csrc + E2;                   // EGAT

  // transposed-split weight offsets (h, l) in wts, ushort units
  ushort* m1Wh = wts + 0;      ushort* m1Wl = wts + 16384;
  ushort* m2Wh = wts + 32768;  ushort* m2Wl = wts + 49152;
  ushort* d1Wh = wts + 65536;  ushort* d1Wl = wts + 81920;
  ushort* d2Wh = wts + 98304;  ushort* d2Wl = wts + 114688;
  ushort* l1Wh = wts + 131072; ushort* l1Wl = wts + 163840;
  ushort* r1Wh = wts + 196608; ushort* r1Wl = wts + 229376;
  ushort* l2Wh = wts + 262144; ushort* l2Wl = wts + 270336;
  ushort* r2Wh = wts + 278528; ushort* r2Wl = wts + 286720;
  ushort* jkWh = wts + 294912; ushort* jkWl = wts + 323584;

  const int BIG = 1 << 30;

  // ---- prep (init + weight split + input split), CSR build, norms ----
  prep_kern<<<(NN + WSEG + NN * 128) / 256, 256, 0, stream>>>(
      dinv, cnt_gcn, cnt_gat,
      W_m1, W_m2, W_d1, W_d2, Wl1, Wr1, Wl2, Wr2, W_jk, wts,
      mm_f, d_sf, inh, inl);
  hist_kern<<<(E2 + EGAT) / 256, 256, 0, stream>>>(
      msM, dsM, mmE, ddE, eidx, ew, dinv, cnt_gcn, cnt_gat);
  scan_kern<<<2, 1024, 0, stream>>>(cnt_gcn, rs_gcn, cur_gcn,
                                    cnt_gat, rs_gat, cur_gat, dinv);
  fill_kern<<<(E2 + EGAT) / 256, 256, 0, stream>>>(
      mmE, ddE, eidx, ew, dinv, cur_gcn, csrc, cw, cur_gat, gsrc);

  // ---- GCN layer 1 ----
  gemm_kern<128, 128, 2, false, false><<<dim3(NN / 64, 2, 1), 256, 0, stream>>>(
      inh, inl, 128, 0, m1Wh, m1Wl, d1Wh, d1Wl, NM, nullptr, h, nullptr, 128);
  gcn_gather_kern<<<NN / 4, 256, 0, stream>>>(
      h, dinv, b_m1, b_d1, rs_gcn, csrc, cw, m1h, m1l, 128);

  // ---- GCN layer 2 -> x0 (split, strided into xjk cols 0..127) ----
  gemm_kern<128, 128, 2, false, false><<<dim3(NN / 64, 2, 1), 256, 0, stream>>>(
      m1h, m1l, 128, 0, m2Wh, m2Wl, d2Wh, d2Wl, NM, nullptr, h, nullptr, 128);
  gcn_gather_kern<<<NN / 4, 256, 0, stream>>>(
      h, dinv, b_m2, b_d2, rs_gcn, csrc, cw, xjkh, xjkl, 224);

  // ---- GATv2 layer 1 (C=64): xl(bf16)/xr(f32) = x0 @ Wl1/Wr1 (dual) ----
  gemm_kern<128, 256, 2, false, true><<<dim3(NN / 64, 2, 2), 256, 0, stream>>>(
      xjkh, xjkl, 224, 0, l1Wh, l1Wl, r1Wh, r1Wl, 0, nullptr, xlb, xr, 256);
  gat_gather_kern<64, true><<<NN, 256, 0, stream>>>(
      xlb, xr, att1, bias1, rs_gat, gsrc, xjkh, xjkl, 224, 128);

  // ---- GATv2 layer 2 (C=32): x1 = xjk cols 128..191 (dual) ----
  gemm_kern<64, 128, 2, false, true><<<dim3(NN / 64, 2, 2), 256, 0, stream>>>(
      xjkh, xjkl, 224, 128, l2Wh, l2Wl, r2Wh, r2Wl, 0, nullptr, xlb, xr, 128);
  gat_gather_kern<32, false><<<NN, 128, 0, stream>>>(
      xlb, xr, att2, bias2, rs_gat, gsrc, xjkh, xjkl, 224, 192);

  // ---- JK linear: out = xjk @ W_jk + b_jk ----
  gemm_kern<224, 128, 2, true, false><<<dim3(NN / 64, 2, 1), 256, 0, stream>>>(
      xjkh, xjkl, 224, 0, jkWh, jkWl, jkWh, jkWl, BIG, b_jk, out, nullptr, 128);
}